// Round 22
// baseline (2022.716 us; speedup 1.0000x reference)
//
#include <hip/hip_runtime.h>
#include <math.h>

#define N_NODES 100000
#define DIM 256
#define ATT 512
#define NH 8
#define HD 64
#define E_PAIRS 250000
#define TYPE_CT 64
#define TS 64
#define P_SEG 8192
#define PC_SEG 1024
#define MP_SZ 131072
#define MC_SZ 16384
#define CD 768  // DIM + ATT

typedef unsigned short u16;
typedef __attribute__((ext_vector_type(8))) short short8v;
typedef __attribute__((ext_vector_type(4))) float floatx4;

// ---------- bf16 helpers (RNE) ----------
__device__ __forceinline__ u16 f2b(float f) {
    unsigned u = __float_as_uint(f);
    return (u16)((u + 0x7FFFu + ((u >> 16) & 1u)) >> 16);
}
__device__ __forceinline__ float b2f(u16 h) {
    return __uint_as_float(((unsigned)h) << 16);
}

template<int N>
__device__ __forceinline__ void waitcnt_vm() {
    asm volatile("s_waitcnt vmcnt(%0)" :: "n"(N) : "memory");
}
// s_barrier WITH compiler memory fence (raw builtin is exec-only).
__device__ __forceinline__ void barrier_fence() {
    asm volatile("s_barrier" ::: "memory");
    __builtin_amdgcn_sched_barrier(0);
}

// XCD-grouping remap: all gx column-blocks of one A-panel (same y) get
// flat%8 == y%8 -> same XCD L2 -> panel fetched once, not gx times.
__device__ __forceinline__ void remap8(int flat, int gx, int& bx, int& by) {
    int yc = flat & 7;
    int t = flat >> 3;
    bx = t % gx;
    by = yc + 8 * (t / gx);
}

// ---------- guard: report ws_size via output ----------
__global__ __launch_bounds__(256) void fill_val_k(float* out, int n, float v) {
    int i = blockIdx.x * 256 + threadIdx.x;
    if (i < n) out[i] = v;
}

// ---------- LayerNorm -> bf16: one wave per row ----------
__global__ __launch_bounds__(64) void layernorm_k(
    const float* __restrict__ ns, const float* __restrict__ g,
    const float* __restrict__ b, u16* __restrict__ x)
{
    int row = blockIdx.x;
    int lane = threadIdx.x;
    float4 v = ((const float4*)(ns + (size_t)row * DIM))[lane];
    float sum = v.x + v.y + v.z + v.w;
    #pragma unroll
    for (int off = 32; off >= 1; off >>= 1) sum += __shfl_xor(sum, off);
    float mu = sum * (1.0f / DIM);
    float dx = v.x - mu, dy = v.y - mu, dz = v.z - mu, dw = v.w - mu;
    float sq = dx * dx + dy * dy + dz * dz + dw * dw;
    #pragma unroll
    for (int off = 32; off >= 1; off >>= 1) sq += __shfl_xor(sq, off);
    float rs = rsqrtf(sq * (1.0f / DIM) + 1e-5f);
    float4 gg = ((const float4*)g)[lane];
    float4 bb = ((const float4*)b)[lane];
    u16 o4[4];
    o4[0] = f2b(dx * rs * gg.x + bb.x);
    o4[1] = f2b(dy * rs * gg.y + bb.y);
    o4[2] = f2b(dz * rs * gg.z + bb.z);
    o4[3] = f2b(dw * rs * gg.w + bb.w);
    *(uint2*)(x + (size_t)row * DIM + lane * 4) = *(uint2*)o4;
}

// ---------- per-type gate table: sigmoid(emb[t] @ W + b) ----------
__global__ __launch_bounds__(512) void gate_table_k(
    const float* __restrict__ emb, const float* __restrict__ w,
    const float* __restrict__ wb, float* __restrict__ tab)
{
    int t = blockIdx.x;
    int a = threadIdx.x;
    float acc = wb[a];
    #pragma unroll 8
    for (int s = 0; s < TS; ++s) acc += emb[t * TS + s] * w[s * ATT + a];
    tab[t * ATT + a] = 1.0f / (1.0f + expf(-acc));
}

// ---------- weight prep: fp32 [K][N] -> bf16 [N][K] ----------
__global__ __launch_bounds__(256) void wcvt_k(
    const float* __restrict__ W, u16* __restrict__ Bt, int K, int N)
{
    int idx = blockIdx.x * 256 + threadIdx.x;
    if (idx >= K * N) return;
    int c = idx / K, k = idx - c * K;
    Bt[idx] = f2b(W[(size_t)k * N + c]);
}

// ---------- QKV weight prep: [H][D][HD] x3 -> [h][{q,k,v}*64][D] bf16 ------
__global__ __launch_bounds__(256) void wqkv_cvt_k(
    const float* __restrict__ Wq, const float* __restrict__ Wk,
    const float* __restrict__ Wv, u16* __restrict__ outp)
{
    int idx = blockIdx.x * 256 + threadIdx.x;  // idx = ((h*3+m)*64+c)*256 + k
    if (idx >= NH * 3 * HD * DIM) return;
    int k = idx & (DIM - 1);
    int c = (idx >> 8) & (HD - 1);
    int hm = idx >> 14;          // = h*3 + m
    int m = hm % 3;
    int h = hm / 3;
    const float* W = (m == 0) ? Wq : ((m == 1) ? Wk : Wv);
    outp[idx] = f2b(W[((size_t)h * DIM + k) * HD + c]);
}

// ---------- MFMA bf16 GEMM, DEPTH-buffer counted-vmcnt pipeline ----------
// Round-13/16 proven config. BM x (32*WN) tile, BK=32, 4 waves, DEPTH-
// buffered linear LDS, global_load_lds 16B staging, chunk-XOR swizzle.
template<int BM, int WN, int DEPTH, int EPI>
__device__ __forceinline__ void gemm_body3(
    int bm, int bn,
    const u16* __restrict__ A, int lda,
    const u16* __restrict__ A2, int lda2, int K1,
    const u16* __restrict__ Bt, int ldb,
    u16* __restrict__ C, int ldc,
    int M, int K,
    const float* __restrict__ bias,
    const float* __restrict__ gateTab,
    const int* __restrict__ types)
{
    constexpr int BN = 32 * WN;
    constexpr int AR = BM / 64;
    constexpr int BR = BN / 64;
    constexpr int LA = AR + BR;
    constexpr int AF = BM / 32;
    __shared__ u16 As[DEPTH][BM * 32];
    __shared__ u16 Bs[DEPTH][BN * 32];
    const int tid = threadIdx.x;
    const int wave = tid >> 6, lane = tid & 63;
    const int wm = (wave >> 1) * (BM / 2), wn = (wave & 1) * 16 * WN;
    const int srow = tid >> 2;
    const int skk = (((tid & 3) ^ ((srow >> 1) & 3)) * 8);
    floatx4 acc[AF][WN] = {};

    auto stage = [&](int buf, int k0) {
        #pragma unroll
        for (int rnd = 0; rnd < AR; ++rnd) {
            int grow = bm + srow + rnd * 64;
            if (grow > M - 1) grow = M - 1;
            int gk = k0 + skk;
            const u16* src;
            if (EPI == 2 && gk >= K1) src = A2 + (size_t)grow * lda2 + (gk - K1);
            else                      src = A + (size_t)grow * lda + gk;
            __builtin_amdgcn_global_load_lds(
                (const __attribute__((address_space(1))) void*)src,
                (__attribute__((address_space(3))) void*)(&As[buf][rnd * 2048 + wave * 512]),
                16, 0, 0);
        }
        #pragma unroll
        for (int rnd = 0; rnd < BR; ++rnd) {
            const u16* src = Bt + (size_t)(bn + srow + rnd * 64) * ldb + k0 + skk;
            __builtin_amdgcn_global_load_lds(
                (const __attribute__((address_space(1))) void*)src,
                (__attribute__((address_space(3))) void*)(&Bs[buf][rnd * 2048 + wave * 512]),
                16, 0, 0);
        }
    };

    const int NS = K >> 5;
    #pragma unroll
    for (int p = 0; p < DEPTH - 1; ++p)
        if (p < NS) stage(p, p * 32);
    const int rr = lane & 15;
    const int cq = lane >> 4;
    int cur = 0;
    for (int is = 0; is < NS; ++is) {
        int pend = NS - 1 - is;
        if (pend > DEPTH - 2) pend = DEPTH - 2;
        if (pend >= 2)      waitcnt_vm<2 * LA>();
        else if (pend == 1) waitcnt_vm<LA>();
        else                waitcnt_vm<0>();
        barrier_fence();
        if (is + DEPTH - 1 < NS) stage((cur + DEPTH - 1) % DEPTH, (is + DEPTH - 1) * 32);
        short8v a[AF], b[WN];
        #pragma unroll
        for (int i = 0; i < AF; ++i) {
            int ar = wm + i * 16 + rr;
            a[i] = *(const short8v*)&As[cur][ar * 32 + ((cq ^ ((ar >> 1) & 3)) * 8)];
        }
        #pragma unroll
        for (int j = 0; j < WN; ++j) {
            int br = wn + j * 16 + rr;
            b[j] = *(const short8v*)&Bs[cur][br * 32 + ((cq ^ ((br >> 1) & 3)) * 8)];
        }
        #pragma unroll
        for (int i = 0; i < AF; ++i)
            #pragma unroll
            for (int j = 0; j < WN; ++j)
                acc[i][j] = __builtin_amdgcn_mfma_f32_16x16x32_bf16(
                    a[i], b[j], acc[i][j], 0, 0, 0);
        cur = (cur + 1) % DEPTH;
    }
    #pragma unroll
    for (int i = 0; i < AF; ++i) {
        #pragma unroll
        for (int j = 0; j < WN; ++j) {
            #pragma unroll
            for (int q = 0; q < 4; ++q) {
                int row = bm + wm + i * 16 + (lane >> 4) * 4 + q;
                if (row >= M) continue;
                int col = bn + wn + j * 16 + (lane & 15);
                float v = acc[i][j][q];
                size_t idx = (size_t)row * ldc + col;
                if (EPI == 0) C[idx] = f2b(v);
                else if (EPI == 1) {
                    float g = gateTab[types[row] * ATT + col];
                    C[idx] = f2b(b2f(C[idx]) + g * v);
                } else if (EPI == 3) {
                    float g = gateTab[types[row] * ATT + col];
                    C[idx] = f2b(g * v);
                } else {
                    C[idx] = f2b(tanhf(v + bias[col]));
                }
            }
        }
    }
}

#define MB64 1563          // (N_NODES + 63) / 64
#define MB64P 1568         // padded to multiple of 8 for remap8

// ---------- named GEMM wrappers (round-16 proven configs) ----------
__global__ __launch_bounds__(256) void gemm_qkv(
    const u16* __restrict__ A, const u16* __restrict__ Bt, u16* __restrict__ C)
{
    gemm_body3<64, 6, 3, 0>(blockIdx.y * 64, 0,
                            A, DIM, nullptr, 0, 1 << 30, Bt, DIM, C, 192,
                            N_NODES, DIM, nullptr, nullptr, nullptr);
}
// batched-heads QKV: gx 192-col blocks (one per head in batch), ldc = gx*192
__global__ __launch_bounds__(256) void gemm_qkv_all(
    const u16* __restrict__ A, const u16* __restrict__ Bt, u16* __restrict__ C,
    int gx)
{
    int bx, by; remap8(blockIdx.x, gx, bx, by);
    if (by >= MB64) return;
    gemm_body3<64, 6, 3, 0>(by * 64, bx * 192,
                            A, DIM, nullptr, 0, 1 << 30, Bt, DIM, C, gx * 192,
                            N_NODES, DIM, nullptr, nullptr, nullptr);
}
__global__ __launch_bounds__(256) void gemm_wo_first(
    const u16* __restrict__ A, const u16* __restrict__ Bt, u16* __restrict__ C,
    const float* __restrict__ gateTab, const int* __restrict__ types)
{
    int bx, by; remap8(blockIdx.x, 4, bx, by);
    if (by >= MB64) return;
    gemm_body3<64, 4, 3, 3>(by * 64, bx * 128,
                            A, ATT, nullptr, 0, 1 << 30, Bt, ATT, C, ATT,
                            N_NODES, ATT, nullptr, gateTab, types);
}
__global__ __launch_bounds__(256) void gemm_wo_acc(
    const u16* __restrict__ A, const u16* __restrict__ Bt, u16* __restrict__ C,
    const float* __restrict__ gateTab, const int* __restrict__ types)
{
    int bx, by; remap8(blockIdx.x, 4, bx, by);
    if (by >= MB64) return;
    gemm_body3<64, 4, 3, 1>(by * 64, bx * 128,
                            A, ATT, nullptr, 0, 1 << 30, Bt, ATT, C, ATT,
                            N_NODES, ATT, nullptr, gateTab, types);
}
// ---- fused dual-Wo GEMM: comb = gp*(Ap@WoP) + gc*(Ac@WoC) ----
// body3 skeleton (BM=64, WN=4, DEPTH=3, LA=3), K=1024 split at 512 into two
// accumulator sets; uniform is<16 select; two-gate epilogue, single write.
__global__ __launch_bounds__(256) void gemm_wo_fused(
    const u16* __restrict__ Ap, const u16* __restrict__ Ac,
    const u16* __restrict__ Btp, const u16* __restrict__ Btc,
    u16* __restrict__ C,
    const float* __restrict__ gtp, const float* __restrict__ gtc,
    const int* __restrict__ types)
{
    int bx, by; remap8(blockIdx.x, 4, bx, by);
    if (by >= MB64) return;
    const int bm = by * 64, bn = bx * 128;
    __shared__ u16 As[3][64 * 32];
    __shared__ u16 Bs[3][128 * 32];
    const int tid = threadIdx.x;
    const int wave = tid >> 6, lane = tid & 63;
    const int wm = (wave >> 1) * 32, wn = (wave & 1) * 64;
    const int srow = tid >> 2;
    const int skk = (((tid & 3) ^ ((srow >> 1) & 3)) * 8);
    floatx4 accP[2][4] = {};
    floatx4 accC[2][4] = {};

    auto stage = [&](int buf, int k0) {
        const u16* Au = (k0 < 512) ? Ap : Ac;
        const u16* Bu = (k0 < 512) ? Btp : Btc;
        int kk = (k0 < 512) ? k0 : (k0 - 512);
        {
            int grow = bm + srow;
            if (grow > N_NODES - 1) grow = N_NODES - 1;
            const u16* src = Au + (size_t)grow * ATT + kk + skk;
            __builtin_amdgcn_global_load_lds(
                (const __attribute__((address_space(1))) void*)src,
                (__attribute__((address_space(3))) void*)(&As[buf][wave * 512]),
                16, 0, 0);
        }
        #pragma unroll
        for (int rnd = 0; rnd < 2; ++rnd) {
            const u16* src = Bu + (size_t)(bn + srow + rnd * 64) * ATT + kk + skk;
            __builtin_amdgcn_global_load_lds(
                (const __attribute__((address_space(1))) void*)src,
                (__attribute__((address_space(3))) void*)(&Bs[buf][rnd * 2048 + wave * 512]),
                16, 0, 0);
        }
    };

    const int NS = 32;
    stage(0, 0);
    stage(1, 32);
    const int rr = lane & 15;
    const int cq = lane >> 4;
    int cur = 0;
    for (int is = 0; is < NS; ++is) {
        if (is < NS - 1) waitcnt_vm<3>();
        else             waitcnt_vm<0>();
        barrier_fence();
        if (is + 2 < NS) stage((cur + 2) % 3, (is + 2) * 32);
        short8v a[2], b[4];
        #pragma unroll
        for (int i = 0; i < 2; ++i) {
            int ar = wm + i * 16 + rr;
            a[i] = *(const short8v*)&As[cur][ar * 32 + ((cq ^ ((ar >> 1) & 3)) * 8)];
        }
        #pragma unroll
        for (int j = 0; j < 4; ++j) {
            int br = wn + j * 16 + rr;
            b[j] = *(const short8v*)&Bs[cur][br * 32 + ((cq ^ ((br >> 1) & 3)) * 8)];
        }
        if (is < 16) {
            #pragma unroll
            for (int i = 0; i < 2; ++i)
                #pragma unroll
                for (int j = 0; j < 4; ++j)
                    accP[i][j] = __builtin_amdgcn_mfma_f32_16x16x32_bf16(
                        a[i], b[j], accP[i][j], 0, 0, 0);
        } else {
            #pragma unroll
            for (int i = 0; i < 2; ++i)
                #pragma unroll
                for (int j = 0; j < 4; ++j)
                    accC[i][j] = __builtin_amdgcn_mfma_f32_16x16x32_bf16(
                        a[i], b[j], accC[i][j], 0, 0, 0);
        }
        cur = (cur + 1) % 3;
    }
    #pragma unroll
    for (int i = 0; i < 2; ++i) {
        #pragma unroll
        for (int j = 0; j < 4; ++j) {
            #pragma unroll
            for (int q = 0; q < 4; ++q) {
                int row = bm + wm + i * 16 + (lane >> 4) * 4 + q;
                if (row >= N_NODES) continue;
                int col = bn + wn + j * 16 + (lane & 15);
                float gp = gtp[types[row] * ATT + col];
                float gc = gtc[types[row] * ATT + col];
                C[(size_t)row * ATT + col] =
                    f2b(gp * accP[i][j][q] + gc * accC[i][j][q]);
            }
        }
    }
}
// dag over a 384-col chunk (2-pass fallback): gx=3
__global__ __launch_bounds__(256) void gemm_dag(
    const u16* __restrict__ A, const u16* __restrict__ A2,
    const u16* __restrict__ Bt, u16* __restrict__ C,
    const float* __restrict__ bias)
{
    int bx, by; remap8(blockIdx.x, 3, bx, by);
    if (by >= MB64) return;
    gemm_body3<64, 4, 3, 2>(by * 64, bx * 128,
                            A, DIM, A2, ATT, DIM, Bt, CD, C, 384,
                            N_NODES, CD, bias, nullptr, nullptr);
}
// dag full 768-col single pass: gx=6, ldc=768
__global__ __launch_bounds__(256) void gemm_dag_full(
    const u16* __restrict__ A, const u16* __restrict__ A2,
    const u16* __restrict__ Bt, u16* __restrict__ C,
    const float* __restrict__ bias)
{
    int bx, by; remap8(blockIdx.x, 6, bx, by);
    if (by >= MB64) return;
    gemm_body3<64, 4, 3, 2>(by * 64, bx * 128,
                            A, DIM, A2, ATT, DIM, Bt, CD, C, CD,
                            N_NODES, CD, bias, nullptr, nullptr);
}

// ---------- CSR build ----------
__global__ __launch_bounds__(256) void count_k(
    const int* __restrict__ src, int* __restrict__ counts)
{
    int e = blockIdx.x * 256 + threadIdx.x;
    if (e < E_PAIRS) atomicAdd(&counts[src[e]], 1);
}
__global__ __launch_bounds__(256) void scan1_k(
    const int* __restrict__ counts, int* __restrict__ offs, int* __restrict__ bsums)
{
    __shared__ int sm[256];
    int i = blockIdx.x * 256 + threadIdx.x;
    int v = (i < N_NODES) ? counts[i] : 0;
    sm[threadIdx.x] = v;
    __syncthreads();
    for (int d = 1; d < 256; d <<= 1) {
        int t = (threadIdx.x >= d) ? sm[threadIdx.x - d] : 0;
        __syncthreads();
        sm[threadIdx.x] += t;
        __syncthreads();
    }
    if (i < N_NODES) offs[i] = sm[threadIdx.x] - v;   // exclusive
    if (threadIdx.x == 255) bsums[blockIdx.x] = sm[255];
}
__global__ __launch_bounds__(512) void scan2_k(int* __restrict__ bsums, int nb)
{
    __shared__ int sm[512];
    int tx = threadIdx.x;
    int v = (tx < nb) ? bsums[tx] : 0;
    sm[tx] = v;
    __syncthreads();
    for (int d = 1; d < 512; d <<= 1) {
        int t = (tx >= d) ? sm[tx - d] : 0;
        __syncthreads();
        sm[tx] += t;
        __syncthreads();
    }
    if (tx < nb) bsums[tx] = sm[tx] - v;              // exclusive
}
__global__ __launch_bounds__(256) void addcur_k(
    int* __restrict__ offs, const int* __restrict__ bsums, int* __restrict__ cur)
{
    int i = blockIdx.x * 256 + threadIdx.x;
    if (i >= N_NODES) return;
    int o = offs[i] + bsums[i >> 8];
    offs[i] = o;
    cur[i] = o;
}
__global__ __launch_bounds__(256) void scatter_k(
    const int* __restrict__ src, const int* __restrict__ tgt,
    int* __restrict__ cur, int* __restrict__ csr_tgt)
{
    int e = blockIdx.x * 256 + threadIdx.x;
    if (e >= E_PAIRS) return;
    int p = atomicAdd(&cur[src[e]], 1);
    csr_tgt[p] = tgt[e];
}

// ---------- fused segment attention: wave per node, online softmax ---------
// 2-deep edge pipeline (round-16/18 proven). MULTI=1: qkv [N][ld] multi-head,
// head = h_in + blockIdx.y, base = qkv + blockIdx.y*192. MULTI=0: [N][192].
template<int MULTI>
__global__ __launch_bounds__(256) void attn_k(
    const u16* __restrict__ qkv, int ld,
    const int* __restrict__ offs, const int* __restrict__ counts,
    const int* __restrict__ csr_tgt, u16* __restrict__ agg, int h_in)
{
    int s = blockIdx.x * 4 + (threadIdx.x >> 6);
    if (s >= N_NODES) return;
    int hy = MULTI ? blockIdx.y : 0;
    int h = h_in + hy;
    const u16* base = qkv + hy * 192;
    int lane = threadIdx.x & 63;
    float q = b2f(base[(size_t)s * ld + lane]) * 0.125f;  // fold 1/sqrt(64)
    int lo = offs[s], deg = counts[s];
    float m = -INFINITY, l = 0.0f, acc = 0.0f;
    if (deg > 0) {
        int t0 = csr_tgt[lo];
        u16 kc = base[(size_t)t0 * ld + 64 + lane];
        u16 vc = base[(size_t)t0 * ld + 128 + lane];
        for (int i = 0; i < deg; ++i) {
            u16 kn = 0, vn = 0;
            if (i + 1 < deg) {
                int tn = csr_tgt[lo + i + 1];
                kn = base[(size_t)tn * ld + 64 + lane];
                vn = base[(size_t)tn * ld + 128 + lane];
            }
            float p = q * b2f(kc);
            #pragma unroll
            for (int off = 32; off >= 1; off >>= 1) p += __shfl_xor(p, off);
            float mn = fmaxf(m, p);
            float sc = expf(m - mn);    // m=-inf first iter -> 0
            float w  = expf(p - mn);
            l = l * sc + w;
            acc = acc * sc + w * b2f(vc);
            m = mn;
            kc = kn; vc = vn;
        }
    }
    float r = (deg > 0) ? acc / l : 0.0f;
    agg[(size_t)s * ATT + h * HD + lane] = f2b(r);
}

// ---------- segment max over ncol cols of pooled (bf16, ld stride) --------
template<int BFOUT>
__global__ __launch_bounds__(256) void seg_max_k(
    const u16* __restrict__ pooled, int ldp, int ncol,
    const int* __restrict__ nodes, const int* __restrict__ seg, int total,
    void* __restrict__ outv, int ldo)
{
    int p = blockIdx.x;
    int lo, hi;
    { int a = 0, b2 = total; while (a < b2) { int mid = (a + b2) >> 1; if (seg[mid] < p) a = mid + 1; else b2 = mid; } lo = a; }
    { int a = lo, b2 = total; while (a < b2) { int mid = (a + b2) >> 1; if (seg[mid] < p + 1) a = mid + 1; else b2 = mid; } hi = a; }
    for (int c = threadIdx.x; c < ncol; c += 256) {
        float mx = -INFINITY;
        for (int i = lo; i < hi; ++i)
            mx = fmaxf(mx, b2f(pooled[(size_t)nodes[i] * ldp + c]));
        if (BFOUT) ((u16*)outv)[(size_t)p * ldo + c] = f2b(mx);
        else       ((float*)outv)[(size_t)p * ldo + c] = mx;
    }
}

// ---------- gather conj rows into second half of output (bf16 -> fp32) ----
__global__ __launch_bounds__(768) void gather_conj(
    const u16* __restrict__ cs, const int* __restrict__ p2c,
    float* __restrict__ out)
{
    int p = blockIdx.x;
    int c = threadIdx.x;
    out[(size_t)p * (2 * CD) + CD + c] = b2f(cs[(size_t)p2c[p] * CD + c]);
}

extern "C" void kernel_launch(void* const* d_in, const int* in_sizes, int n_in,
                              void* d_out, int out_size, void* d_ws, size_t ws_size,
                              hipStream_t stream) {
    const float* node_states     = (const float*)d_in[0];
    const int*   node_types      = (const int*)d_in[1];
    const int*   pair_conj       = (const int*)d_in[2];
    const int*   pair_prem       = (const int*)d_in[3];
    const int*   pool_prem_nodes = (const int*)d_in[4];
    const int*   pool_prem_seg   = (const int*)d_in[5];
    const int*   pool_conj_nodes = (const int*)d_in[6];
    const int*   pool_conj_seg   = (const int*)d_in[7];
    const int*   prem2conj       = (const int*)d_in[8];
    const float* ln_g  = (const float*)d_in[9];
    const float* ln_b  = (const float*)d_in[10];
    const float* emb_p = (const float*)d_in[11];
    const float* wp_w  = (const float*)d_in[12];
    const float* wp_b  = (const float*)d_in[13];
    const float* emb_c = (const float*)d_in[14];
    const float* wc_w  = (const float*)d_in[15];
    const float* wc_b  = (const float*)d_in[16];
    const float* Wq_p  = (const float*)d_in[17];
    const float* Wk_p  = (const float*)d_in[18];
    const float* Wv_p  = (const float*)d_in[19];
    const float* Wo_p  = (const float*)d_in[20];
    const float* Wq_c  = (const float*)d_in[21];
    const float* Wk_c  = (const float*)d_in[22];
    const float* Wv_c  = (const float*)d_in[23];
    const float* Wo_c  = (const float*)d_in[24];
    const float* W_dag = (const float*)d_in[25];
    const float* b_dag = (const float*)d_in[26];
    float* out = (float*)d_out;

    // ===== workspace layout (bytes) =====
    char* ws = (char*)d_ws;
    size_t o = 0;
    u16* x_bf  = (u16*)(ws + o); o += (size_t)N_NODES * DIM * 2;   // 51.2 MB
    u16* comb  = (u16*)(ws + o); o += (size_t)N_NODES * ATT * 2;   // 102.4 MB
    u16* R     = (u16*)(ws + o); o += (size_t)N_NODES * ATT * 2;   // 102.4 MB (agg / pooled)
    char* csrb = ws + o;         o += 8000000;                     // CSR, later wdag_t
    u16* conj_sets = (u16*)(ws + o); o += (size_t)PC_SEG * CD * 2; // 1.57 MB
    const size_t WS_NEEDED = o;

    if (ws_size < WS_NEEDED) {
        fill_val_k<<<(out_size + 255) / 256, 256, 0, stream>>>(out, out_size, (float)ws_size);
        return;
    }
    // graduated head-batch: qkv_batch buffer [N][batch*192] bf16 appended
    u16* qkv_all = (u16*)(ws + WS_NEEDED);
    int batch = 1;
    if (ws_size >= WS_NEEDED + (size_t)N_NODES * 1536 * 2)      batch = 8;
    else if (ws_size >= WS_NEEDED + (size_t)N_NODES * 768 * 2)  batch = 4;
    else if (ws_size >= WS_NEEDED + (size_t)N_NODES * 384 * 2)  batch = 2;
    // fused dual-Wo path (batch-4 qkv layout): qkv_all [N][768] (153.6 MB)
    // + aggC [N][512] (102.4 MB) beyond base = 521.6 MB total.
    u16* aggC = qkv_all + (size_t)N_NODES * 768;   // u16 elements
    const bool fused = (batch >= 4) &&
        (ws_size >= WS_NEEDED + (size_t)N_NODES * 768 * 2
                  + (size_t)N_NODES * ATT * 2);
    // batch>=4 (or fused) -> qkv_all region can host full pooled [N][768]
    u16* pooled_full = qkv_all;

    u16* agg    = R;
    u16* pooled = R;
    int* c_counts[2], *c_offs[2], *c_cur[2], *c_tgt[2];
    for (int d = 0; d < 2; ++d) {
        char* base = csrb + (size_t)d * 2200000;
        c_counts[d] = (int*)(base + 0);
        c_offs[d]   = (int*)(base + 400000);
        c_cur[d]    = (int*)(base + 800000);
        c_tgt[d]    = (int*)(base + 1200000);
    }
    int* bsums = (int*)(csrb + 4400000);
    u16* wdag_t = (u16*)csrb;   // overwrites CSR after attention is done

    // ===== d_out scratch (all dead before first final-output write) =====
    char* ob = (char*)d_out;
    u16* qkv     = (u16*)(ob + 0);          // 38.4 MB [N][q|k|v] one head
    float* gtab_p = (float*)(ob + 38400000);
    float* gtab_c = (float*)(ob + 38531072);
    u16* wqkv_t  = (u16*)(ob + 38662144);   // 1.57 MB (2 dirs)
    u16* wo_t    = (u16*)(ob + 40235008);   // 2.10 MB (2 dirs)
    // end 42,332,160 <= 50,331,648

    // ---- prep ----
    layernorm_k<<<N_NODES, 64, 0, stream>>>(node_states, ln_g, ln_b, x_bf);
    gate_table_k<<<TYPE_CT, ATT, 0, stream>>>(emb_p, wp_w, wp_b, gtab_p);
    gate_table_k<<<TYPE_CT, ATT, 0, stream>>>(emb_c, wc_w, wc_b, gtab_c);
    wqkv_cvt_k<<<(NH * 3 * HD * DIM + 255) / 256, 256, 0, stream>>>(
        Wq_p, Wk_p, Wv_p, wqkv_t);
    wqkv_cvt_k<<<(NH * 3 * HD * DIM + 255) / 256, 256, 0, stream>>>(
        Wq_c, Wk_c, Wv_c, wqkv_t + (size_t)NH * 3 * HD * DIM);
    wcvt_k<<<(ATT * ATT + 255) / 256, 256, 0, stream>>>(Wo_p, wo_t, ATT, ATT);
    wcvt_k<<<(ATT * ATT + 255) / 256, 256, 0, stream>>>(
        Wo_c, wo_t + (size_t)ATT * ATT, ATT, ATT);

    // ---- CSR build for both dirs (src = query side) ----
    const int NSCAN = (N_NODES + 255) / 256;  // 391
    for (int d = 0; d < 2; ++d) {
        const int* src = d ? pair_conj : pair_prem;
        const int* tgt = d ? pair_prem : pair_conj;
        hipMemsetAsync(c_counts[d], 0, 400000, stream);
        count_k<<<(E_PAIRS + 255) / 256, 256, 0, stream>>>(src, c_counts[d]);
        scan1_k<<<NSCAN, 256, 0, stream>>>(c_counts[d], c_offs[d], bsums);
        scan2_k<<<1, 512, 0, stream>>>(bsums, NSCAN);
        addcur_k<<<NSCAN, 256, 0, stream>>>(c_offs[d], bsums, c_cur[d]);
        scatter_k<<<(E_PAIRS + 255) / 256, 256, 0, stream>>>(src, tgt, c_cur[d], c_tgt[d]);
    }

    if (fused) {
        // batch-4 qkv chunks (region [N][768]); both dirs' attention first,
        // then one fused dual-Wo GEMM (no comb RMW, single write pass).
        for (int dir = 0; dir < 2; ++dir) {
            const u16* wq_d = wqkv_t + (size_t)dir * NH * 3 * HD * DIM;
            u16* agg_d = dir ? aggC : agg;
            for (int hb = 0; hb < NH; hb += 4) {
                gemm_qkv_all<<<4 * MB64P, 256, 0, stream>>>(
                    x_bf, wq_d + (size_t)hb * 3 * HD * DIM, qkv_all, 4);
                attn_k<1><<<dim3((N_NODES + 3) / 4, 4), 256, 0, stream>>>(
                    qkv_all, 768, c_offs[dir], c_counts[dir], c_tgt[dir],
                    agg_d, hb);
            }
        }
        gemm_wo_fused<<<4 * MB64P, 256, 0, stream>>>(
            agg, aggC, wo_t, wo_t + (size_t)ATT * ATT, comb,
            gtab_p, gtab_c, node_types);
    } else {
        for (int dir = 0; dir < 2; ++dir) {
            const float* gt = dir ? gtab_c : gtab_p;
            const u16* wq_d = wqkv_t + (size_t)dir * NH * 3 * HD * DIM;
            const u16* wo_d = wo_t + (size_t)dir * ATT * ATT;

            if (batch > 1) {
                for (int hb = 0; hb < NH; hb += batch) {
                    gemm_qkv_all<<<batch * MB64P, 256, 0, stream>>>(
                        x_bf, wq_d + (size_t)hb * 3 * HD * DIM, qkv_all, batch);
                    attn_k<1><<<dim3((N_NODES + 3) / 4, batch), 256, 0, stream>>>(
                        qkv_all, batch * 192, c_offs[dir], c_counts[dir],
                        c_tgt[dir], agg, hb);
                }
            } else {
                for (int h = 0; h < NH; ++h) {
                    gemm_qkv<<<dim3(1, MB64), 256, 0, stream>>>(
                        x_bf, wq_d + (size_t)h * 3 * HD * DIM, qkv);
                    attn_k<0><<<(N_NODES + 3) / 4, 256, 0, stream>>>(
                        qkv, 192, c_offs[dir], c_counts[dir], c_tgt[dir], agg, h);
                }
            }

            if (dir == 0)
                gemm_wo_first<<<4 * MB64P, 256, 0, stream>>>(
                    agg, wo_d, comb, gt, node_types);
            else
                gemm_wo_acc<<<4 * MB64P, 256, 0, stream>>>(
                    agg, wo_d, comb, gt, node_types);
        }
    }

    // ---- W_dag -> bf16 [col][k] into CSR region (CSR dead now) ----
    wcvt_k<<<(CD * CD + 255) / 256, 256, 0, stream>>>(W_dag, wdag_t, CD, CD);

    if (batch >= 4) {
        // single-pass dag into the (dead) qkv_all region: halves x|comb re-fetch
        gemm_dag_full<<<6 * MB64P, 256, 0, stream>>>(
            x_bf, comb, wdag_t, pooled_full, b_dag);
        seg_max_k<0><<<P_SEG, 256, 0, stream>>>(
            pooled_full, CD, CD, pool_prem_nodes, pool_prem_seg, MP_SZ, out, 2 * CD);
        seg_max_k<1><<<PC_SEG, 256, 0, stream>>>(
            pooled_full, CD, CD, pool_conj_nodes, pool_conj_seg, MC_SZ, conj_sets, CD);
    } else {
        for (int c0 = 0; c0 < CD; c0 += 384) {
            gemm_dag<<<3 * MB64P, 256, 0, stream>>>(
                x_bf, comb, wdag_t + (size_t)c0 * CD, pooled, b_dag + c0);
            seg_max_k<0><<<P_SEG, 256, 0, stream>>>(
                pooled, 384, 384, pool_prem_nodes, pool_prem_seg, MP_SZ, out + c0, 2 * CD);
            seg_max_k<1><<<PC_SEG, 256, 0, stream>>>(
                pooled, 384, 384, pool_conj_nodes, pool_conj_seg, MC_SZ, conj_sets + c0, CD);
        }
    }
    gather_conj<<<P_SEG, CD, 0, stream>>>(conj_sets, prem2conj, out);
}

// Round 23
// 1983.688 us; speedup vs baseline: 1.0197x; 1.0197x over previous
//
#include <hip/hip_runtime.h>
#include <math.h>

#define N_NODES 100000
#define DIM 256
#define ATT 512
#define NH 8
#define HD 64
#define E_PAIRS 250000
#define TYPE_CT 64
#define TS 64
#define P_SEG 8192
#define PC_SEG 1024
#define MP_SZ 131072
#define MC_SZ 16384
#define CD 768  // DIM + ATT

typedef unsigned short u16;
typedef __attribute__((ext_vector_type(8))) short short8v;
typedef __attribute__((ext_vector_type(4))) float floatx4;

// ---------- bf16 helpers (RNE) ----------
__device__ __forceinline__ u16 f2b(float f) {
    unsigned u = __float_as_uint(f);
    return (u16)((u + 0x7FFFu + ((u >> 16) & 1u)) >> 16);
}
__device__ __forceinline__ float b2f(u16 h) {
    return __uint_as_float(((unsigned)h) << 16);
}

template<int N>
__device__ __forceinline__ void waitcnt_vm() {
    asm volatile("s_waitcnt vmcnt(%0)" :: "n"(N) : "memory");
}
// s_barrier WITH compiler memory fence (raw builtin is exec-only).
__device__ __forceinline__ void barrier_fence() {
    asm volatile("s_barrier" ::: "memory");
    __builtin_amdgcn_sched_barrier(0);
}

// XCD-grouping remap: all gx column-blocks of one A-panel (same y) get
// flat%8 == y%8 -> same XCD L2 -> panel fetched once, not gx times.
__device__ __forceinline__ void remap8(int flat, int gx, int& bx, int& by) {
    int yc = flat & 7;
    int t = flat >> 3;
    bx = t % gx;
    by = yc + 8 * (t / gx);
}

// ---------- guard: report ws_size via output ----------
__global__ __launch_bounds__(256) void fill_val_k(float* out, int n, float v) {
    int i = blockIdx.x * 256 + threadIdx.x;
    if (i < n) out[i] = v;
}

// ---------- LayerNorm -> bf16: one wave per row ----------
__global__ __launch_bounds__(64) void layernorm_k(
    const float* __restrict__ ns, const float* __restrict__ g,
    const float* __restrict__ b, u16* __restrict__ x)
{
    int row = blockIdx.x;
    int lane = threadIdx.x;
    float4 v = ((const float4*)(ns + (size_t)row * DIM))[lane];
    float sum = v.x + v.y + v.z + v.w;
    #pragma unroll
    for (int off = 32; off >= 1; off >>= 1) sum += __shfl_xor(sum, off);
    float mu = sum * (1.0f / DIM);
    float dx = v.x - mu, dy = v.y - mu, dz = v.z - mu, dw = v.w - mu;
    float sq = dx * dx + dy * dy + dz * dz + dw * dw;
    #pragma unroll
    for (int off = 32; off >= 1; off >>= 1) sq += __shfl_xor(sq, off);
    float rs = rsqrtf(sq * (1.0f / DIM) + 1e-5f);
    float4 gg = ((const float4*)g)[lane];
    float4 bb = ((const float4*)b)[lane];
    u16 o4[4];
    o4[0] = f2b(dx * rs * gg.x + bb.x);
    o4[1] = f2b(dy * rs * gg.y + bb.y);
    o4[2] = f2b(dz * rs * gg.z + bb.z);
    o4[3] = f2b(dw * rs * gg.w + bb.w);
    *(uint2*)(x + (size_t)row * DIM + lane * 4) = *(uint2*)o4;
}

// ---------- per-type gate table: sigmoid(emb[t] @ W + b) ----------
__global__ __launch_bounds__(512) void gate_table_k(
    const float* __restrict__ emb, const float* __restrict__ w,
    const float* __restrict__ wb, float* __restrict__ tab)
{
    int t = blockIdx.x;
    int a = threadIdx.x;
    float acc = wb[a];
    #pragma unroll 8
    for (int s = 0; s < TS; ++s) acc += emb[t * TS + s] * w[s * ATT + a];
    tab[t * ATT + a] = 1.0f / (1.0f + expf(-acc));
}

// ---------- weight prep: fp32 [K][N] -> bf16 [N][K] ----------
__global__ __launch_bounds__(256) void wcvt_k(
    const float* __restrict__ W, u16* __restrict__ Bt, int K, int N)
{
    int idx = blockIdx.x * 256 + threadIdx.x;
    if (idx >= K * N) return;
    int c = idx / K, k = idx - c * K;
    Bt[idx] = f2b(W[(size_t)k * N + c]);
}

// ---------- QKV weight prep: [H][D][HD] x3 -> [h][{q,k,v}*64][D] bf16 ------
__global__ __launch_bounds__(256) void wqkv_cvt_k(
    const float* __restrict__ Wq, const float* __restrict__ Wk,
    const float* __restrict__ Wv, u16* __restrict__ outp)
{
    int idx = blockIdx.x * 256 + threadIdx.x;  // idx = ((h*3+m)*64+c)*256 + k
    if (idx >= NH * 3 * HD * DIM) return;
    int k = idx & (DIM - 1);
    int c = (idx >> 8) & (HD - 1);
    int hm = idx >> 14;          // = h*3 + m
    int m = hm % 3;
    int h = hm / 3;
    const float* W = (m == 0) ? Wq : ((m == 1) ? Wk : Wv);
    outp[idx] = f2b(W[((size_t)h * DIM + k) * HD + c]);
}

// ---------- MFMA bf16 GEMM, DEPTH-buffer counted-vmcnt pipeline ----------
// Round-13/16 proven config. BM x (32*WN) tile, BK=32, 4 waves, DEPTH-
// buffered linear LDS, global_load_lds 16B staging, chunk-XOR swizzle.
template<int BM, int WN, int DEPTH, int EPI>
__device__ __forceinline__ void gemm_body3(
    int bm, int bn,
    const u16* __restrict__ A, int lda,
    const u16* __restrict__ A2, int lda2, int K1,
    const u16* __restrict__ Bt, int ldb,
    u16* __restrict__ C, int ldc,
    int M, int K,
    const float* __restrict__ bias,
    const float* __restrict__ gateTab,
    const int* __restrict__ types)
{
    constexpr int BN = 32 * WN;
    constexpr int AR = BM / 64;
    constexpr int BR = BN / 64;
    constexpr int LA = AR + BR;
    constexpr int AF = BM / 32;
    __shared__ u16 As[DEPTH][BM * 32];
    __shared__ u16 Bs[DEPTH][BN * 32];
    const int tid = threadIdx.x;
    const int wave = tid >> 6, lane = tid & 63;
    const int wm = (wave >> 1) * (BM / 2), wn = (wave & 1) * 16 * WN;
    const int srow = tid >> 2;
    const int skk = (((tid & 3) ^ ((srow >> 1) & 3)) * 8);
    floatx4 acc[AF][WN] = {};

    auto stage = [&](int buf, int k0) {
        #pragma unroll
        for (int rnd = 0; rnd < AR; ++rnd) {
            int grow = bm + srow + rnd * 64;
            if (grow > M - 1) grow = M - 1;
            int gk = k0 + skk;
            const u16* src;
            if (EPI == 2 && gk >= K1) src = A2 + (size_t)grow * lda2 + (gk - K1);
            else                      src = A + (size_t)grow * lda + gk;
            __builtin_amdgcn_global_load_lds(
                (const __attribute__((address_space(1))) void*)src,
                (__attribute__((address_space(3))) void*)(&As[buf][rnd * 2048 + wave * 512]),
                16, 0, 0);
        }
        #pragma unroll
        for (int rnd = 0; rnd < BR; ++rnd) {
            const u16* src = Bt + (size_t)(bn + srow + rnd * 64) * ldb + k0 + skk;
            __builtin_amdgcn_global_load_lds(
                (const __attribute__((address_space(1))) void*)src,
                (__attribute__((address_space(3))) void*)(&Bs[buf][rnd * 2048 + wave * 512]),
                16, 0, 0);
        }
    };

    const int NS = K >> 5;
    #pragma unroll
    for (int p = 0; p < DEPTH - 1; ++p)
        if (p < NS) stage(p, p * 32);
    const int rr = lane & 15;
    const int cq = lane >> 4;
    int cur = 0;
    for (int is = 0; is < NS; ++is) {
        int pend = NS - 1 - is;
        if (pend > DEPTH - 2) pend = DEPTH - 2;
        if (pend >= 2)      waitcnt_vm<2 * LA>();
        else if (pend == 1) waitcnt_vm<LA>();
        else                waitcnt_vm<0>();
        barrier_fence();
        if (is + DEPTH - 1 < NS) stage((cur + DEPTH - 1) % DEPTH, (is + DEPTH - 1) * 32);
        short8v a[AF], b[WN];
        #pragma unroll
        for (int i = 0; i < AF; ++i) {
            int ar = wm + i * 16 + rr;
            a[i] = *(const short8v*)&As[cur][ar * 32 + ((cq ^ ((ar >> 1) & 3)) * 8)];
        }
        #pragma unroll
        for (int j = 0; j < WN; ++j) {
            int br = wn + j * 16 + rr;
            b[j] = *(const short8v*)&Bs[cur][br * 32 + ((cq ^ ((br >> 1) & 3)) * 8)];
        }
        #pragma unroll
        for (int i = 0; i < AF; ++i)
            #pragma unroll
            for (int j = 0; j < WN; ++j)
                acc[i][j] = __builtin_amdgcn_mfma_f32_16x16x32_bf16(
                    a[i], b[j], acc[i][j], 0, 0, 0);
        cur = (cur + 1) % DEPTH;
    }
    #pragma unroll
    for (int i = 0; i < AF; ++i) {
        #pragma unroll
        for (int j = 0; j < WN; ++j) {
            #pragma unroll
            for (int q = 0; q < 4; ++q) {
                int row = bm + wm + i * 16 + (lane >> 4) * 4 + q;
                if (row >= M) continue;
                int col = bn + wn + j * 16 + (lane & 15);
                float v = acc[i][j][q];
                size_t idx = (size_t)row * ldc + col;
                if (EPI == 0) C[idx] = f2b(v);
                else if (EPI == 1) {
                    float g = gateTab[types[row] * ATT + col];
                    C[idx] = f2b(b2f(C[idx]) + g * v);
                } else if (EPI == 3) {
                    float g = gateTab[types[row] * ATT + col];
                    C[idx] = f2b(g * v);
                } else {
                    C[idx] = f2b(tanhf(v + bias[col]));
                }
            }
        }
    }
}

#define MB64 1563          // (N_NODES + 63) / 64
#define MB64P 1568         // padded to multiple of 8 for remap8

// ---------- named GEMM wrappers (round-16 proven configs) ----------
__global__ __launch_bounds__(256) void gemm_qkv(
    const u16* __restrict__ A, const u16* __restrict__ Bt, u16* __restrict__ C)
{
    gemm_body3<64, 6, 3, 0>(blockIdx.y * 64, 0,
                            A, DIM, nullptr, 0, 1 << 30, Bt, DIM, C, 192,
                            N_NODES, DIM, nullptr, nullptr, nullptr);
}
// batched-heads QKV: gx 192-col blocks (one per head in batch), ldc = gx*192
__global__ __launch_bounds__(256) void gemm_qkv_all(
    const u16* __restrict__ A, const u16* __restrict__ Bt, u16* __restrict__ C,
    int gx)
{
    int bx, by; remap8(blockIdx.x, gx, bx, by);
    if (by >= MB64) return;
    gemm_body3<64, 6, 3, 0>(by * 64, bx * 192,
                            A, DIM, nullptr, 0, 1 << 30, Bt, DIM, C, gx * 192,
                            N_NODES, DIM, nullptr, nullptr, nullptr);
}
__global__ __launch_bounds__(256) void gemm_wo_first(
    const u16* __restrict__ A, const u16* __restrict__ Bt, u16* __restrict__ C,
    const float* __restrict__ gateTab, const int* __restrict__ types)
{
    int bx, by; remap8(blockIdx.x, 4, bx, by);
    if (by >= MB64) return;
    gemm_body3<64, 4, 3, 3>(by * 64, bx * 128,
                            A, ATT, nullptr, 0, 1 << 30, Bt, ATT, C, ATT,
                            N_NODES, ATT, nullptr, gateTab, types);
}
__global__ __launch_bounds__(256) void gemm_wo_acc(
    const u16* __restrict__ A, const u16* __restrict__ Bt, u16* __restrict__ C,
    const float* __restrict__ gateTab, const int* __restrict__ types)
{
    int bx, by; remap8(blockIdx.x, 4, bx, by);
    if (by >= MB64) return;
    gemm_body3<64, 4, 3, 1>(by * 64, bx * 128,
                            A, ATT, nullptr, 0, 1 << 30, Bt, ATT, C, ATT,
                            N_NODES, ATT, nullptr, gateTab, types);
}
// ---- fused dual-Wo GEMM: comb = gp*(Ap@WoP) + gc*(Ac@WoC) ----
// body3 skeleton (BM=64, WN=4, DEPTH=3, LA=3), K=1024 split at 512 into two
// accumulator sets; uniform is<16 select; two-gate epilogue, single write.
__global__ __launch_bounds__(256) void gemm_wo_fused(
    const u16* __restrict__ Ap, const u16* __restrict__ Ac,
    const u16* __restrict__ Btp, const u16* __restrict__ Btc,
    u16* __restrict__ C,
    const float* __restrict__ gtp, const float* __restrict__ gtc,
    const int* __restrict__ types)
{
    int bx, by; remap8(blockIdx.x, 4, bx, by);
    if (by >= MB64) return;
    const int bm = by * 64, bn = bx * 128;
    __shared__ u16 As[3][64 * 32];
    __shared__ u16 Bs[3][128 * 32];
    const int tid = threadIdx.x;
    const int wave = tid >> 6, lane = tid & 63;
    const int wm = (wave >> 1) * 32, wn = (wave & 1) * 64;
    const int srow = tid >> 2;
    const int skk = (((tid & 3) ^ ((srow >> 1) & 3)) * 8);
    floatx4 accP[2][4] = {};
    floatx4 accC[2][4] = {};

    auto stage = [&](int buf, int k0) {
        const u16* Au = (k0 < 512) ? Ap : Ac;
        const u16* Bu = (k0 < 512) ? Btp : Btc;
        int kk = (k0 < 512) ? k0 : (k0 - 512);
        {
            int grow = bm + srow;
            if (grow > N_NODES - 1) grow = N_NODES - 1;
            const u16* src = Au + (size_t)grow * ATT + kk + skk;
            __builtin_amdgcn_global_load_lds(
                (const __attribute__((address_space(1))) void*)src,
                (__attribute__((address_space(3))) void*)(&As[buf][wave * 512]),
                16, 0, 0);
        }
        #pragma unroll
        for (int rnd = 0; rnd < 2; ++rnd) {
            const u16* src = Bu + (size_t)(bn + srow + rnd * 64) * ATT + kk + skk;
            __builtin_amdgcn_global_load_lds(
                (const __attribute__((address_space(1))) void*)src,
                (__attribute__((address_space(3))) void*)(&Bs[buf][rnd * 2048 + wave * 512]),
                16, 0, 0);
        }
    };

    const int NS = 32;
    stage(0, 0);
    stage(1, 32);
    const int rr = lane & 15;
    const int cq = lane >> 4;
    int cur = 0;
    for (int is = 0; is < NS; ++is) {
        if (is < NS - 1) waitcnt_vm<3>();
        else             waitcnt_vm<0>();
        barrier_fence();
        if (is + 2 < NS) stage((cur + 2) % 3, (is + 2) * 32);
        short8v a[2], b[4];
        #pragma unroll
        for (int i = 0; i < 2; ++i) {
            int ar = wm + i * 16 + rr;
            a[i] = *(const short8v*)&As[cur][ar * 32 + ((cq ^ ((ar >> 1) & 3)) * 8)];
        }
        #pragma unroll
        for (int j = 0; j < 4; ++j) {
            int br = wn + j * 16 + rr;
            b[j] = *(const short8v*)&Bs[cur][br * 32 + ((cq ^ ((br >> 1) & 3)) * 8)];
        }
        if (is < 16) {
            #pragma unroll
            for (int i = 0; i < 2; ++i)
                #pragma unroll
                for (int j = 0; j < 4; ++j)
                    accP[i][j] = __builtin_amdgcn_mfma_f32_16x16x32_bf16(
                        a[i], b[j], accP[i][j], 0, 0, 0);
        } else {
            #pragma unroll
            for (int i = 0; i < 2; ++i)
                #pragma unroll
                for (int j = 0; j < 4; ++j)
                    accC[i][j] = __builtin_amdgcn_mfma_f32_16x16x32_bf16(
                        a[i], b[j], accC[i][j], 0, 0, 0);
        }
        cur = (cur + 1) % 3;
    }
    #pragma unroll
    for (int i = 0; i < 2; ++i) {
        #pragma unroll
        for (int j = 0; j < 4; ++j) {
            #pragma unroll
            for (int q = 0; q < 4; ++q) {
                int row = bm + wm + i * 16 + (lane >> 4) * 4 + q;
                if (row >= N_NODES) continue;
                int col = bn + wn + j * 16 + (lane & 15);
                float gp = gtp[types[row] * ATT + col];
                float gc = gtc[types[row] * ATT + col];
                C[(size_t)row * ATT + col] =
                    f2b(gp * accP[i][j][q] + gc * accC[i][j][q]);
            }
        }
    }
}
// dag over a 384-col chunk (2-pass fallback): gx=3
__global__ __launch_bounds__(256) void gemm_dag(
    const u16* __restrict__ A, const u16* __restrict__ A2,
    const u16* __restrict__ Bt, u16* __restrict__ C,
    const float* __restrict__ bias)
{
    int bx, by; remap8(blockIdx.x, 3, bx, by);
    if (by >= MB64) return;
    gemm_body3<64, 4, 3, 2>(by * 64, bx * 128,
                            A, DIM, A2, ATT, DIM, Bt, CD, C, 384,
                            N_NODES, CD, bias, nullptr, nullptr);
}
// dag full 768-col single pass: gx=6, ldc=768
__global__ __launch_bounds__(256) void gemm_dag_full(
    const u16* __restrict__ A, const u16* __restrict__ A2,
    const u16* __restrict__ Bt, u16* __restrict__ C,
    const float* __restrict__ bias)
{
    int bx, by; remap8(blockIdx.x, 6, bx, by);
    if (by >= MB64) return;
    gemm_body3<64, 4, 3, 2>(by * 64, bx * 128,
                            A, DIM, A2, ATT, DIM, Bt, CD, C, CD,
                            N_NODES, CD, bias, nullptr, nullptr);
}

// ---------- CSR build ----------
__global__ __launch_bounds__(256) void count_k(
    const int* __restrict__ src, int* __restrict__ counts)
{
    int e = blockIdx.x * 256 + threadIdx.x;
    if (e < E_PAIRS) atomicAdd(&counts[src[e]], 1);
}
__global__ __launch_bounds__(256) void scan1_k(
    const int* __restrict__ counts, int* __restrict__ offs, int* __restrict__ bsums)
{
    __shared__ int sm[256];
    int i = blockIdx.x * 256 + threadIdx.x;
    int v = (i < N_NODES) ? counts[i] : 0;
    sm[threadIdx.x] = v;
    __syncthreads();
    for (int d = 1; d < 256; d <<= 1) {
        int t = (threadIdx.x >= d) ? sm[threadIdx.x - d] : 0;
        __syncthreads();
        sm[threadIdx.x] += t;
        __syncthreads();
    }
    if (i < N_NODES) offs[i] = sm[threadIdx.x] - v;   // exclusive
    if (threadIdx.x == 255) bsums[blockIdx.x] = sm[255];
}
__global__ __launch_bounds__(512) void scan2_k(int* __restrict__ bsums, int nb)
{
    __shared__ int sm[512];
    int tx = threadIdx.x;
    int v = (tx < nb) ? bsums[tx] : 0;
    sm[tx] = v;
    __syncthreads();
    for (int d = 1; d < 512; d <<= 1) {
        int t = (tx >= d) ? sm[tx - d] : 0;
        __syncthreads();
        sm[tx] += t;
        __syncthreads();
    }
    if (tx < nb) bsums[tx] = sm[tx] - v;              // exclusive
}
__global__ __launch_bounds__(256) void addcur_k(
    int* __restrict__ offs, const int* __restrict__ bsums, int* __restrict__ cur)
{
    int i = blockIdx.x * 256 + threadIdx.x;
    if (i >= N_NODES) return;
    int o = offs[i] + bsums[i >> 8];
    offs[i] = o;
    cur[i] = o;
}
__global__ __launch_bounds__(256) void scatter_k(
    const int* __restrict__ src, const int* __restrict__ tgt,
    int* __restrict__ cur, int* __restrict__ csr_tgt)
{
    int e = blockIdx.x * 256 + threadIdx.x;
    if (e >= E_PAIRS) return;
    int p = atomicAdd(&cur[src[e]], 1);
    csr_tgt[p] = tgt[e];
}

// ---------- fused segment attention: wave per node, online softmax ---------
// 2-deep edge pipeline (round-16/18 proven). MULTI=1: qkv [N][ld] multi-head,
// head = h_in + blockIdx.y, base = qkv + blockIdx.y*192. MULTI=0: [N][192].
template<int MULTI>
__global__ __launch_bounds__(256) void attn_k(
    const u16* __restrict__ qkv, int ld,
    const int* __restrict__ offs, const int* __restrict__ counts,
    const int* __restrict__ csr_tgt, u16* __restrict__ agg, int h_in)
{
    int s = blockIdx.x * 4 + (threadIdx.x >> 6);
    if (s >= N_NODES) return;
    int hy = MULTI ? blockIdx.y : 0;
    int h = h_in + hy;
    const u16* base = qkv + hy * 192;
    int lane = threadIdx.x & 63;
    float q = b2f(base[(size_t)s * ld + lane]) * 0.125f;  // fold 1/sqrt(64)
    int lo = offs[s], deg = counts[s];
    float m = -INFINITY, l = 0.0f, acc = 0.0f;
    if (deg > 0) {
        int t0 = csr_tgt[lo];
        u16 kc = base[(size_t)t0 * ld + 64 + lane];
        u16 vc = base[(size_t)t0 * ld + 128 + lane];
        for (int i = 0; i < deg; ++i) {
            u16 kn = 0, vn = 0;
            if (i + 1 < deg) {
                int tn = csr_tgt[lo + i + 1];
                kn = base[(size_t)tn * ld + 64 + lane];
                vn = base[(size_t)tn * ld + 128 + lane];
            }
            float p = q * b2f(kc);
            #pragma unroll
            for (int off = 32; off >= 1; off >>= 1) p += __shfl_xor(p, off);
            float mn = fmaxf(m, p);
            float sc = expf(m - mn);    // m=-inf first iter -> 0
            float w  = expf(p - mn);
            l = l * sc + w;
            acc = acc * sc + w * b2f(vc);
            m = mn;
            kc = kn; vc = vn;
        }
    }
    float r = (deg > 0) ? acc / l : 0.0f;
    agg[(size_t)s * ATT + h * HD + lane] = f2b(r);
}

// ---------- segment max over ncol cols of pooled (bf16, ld stride) --------
template<int BFOUT>
__global__ __launch_bounds__(256) void seg_max_k(
    const u16* __restrict__ pooled, int ldp, int ncol,
    const int* __restrict__ nodes, const int* __restrict__ seg, int total,
    void* __restrict__ outv, int ldo)
{
    int p = blockIdx.x;
    int lo, hi;
    { int a = 0, b2 = total; while (a < b2) { int mid = (a + b2) >> 1; if (seg[mid] < p) a = mid + 1; else b2 = mid; } lo = a; }
    { int a = lo, b2 = total; while (a < b2) { int mid = (a + b2) >> 1; if (seg[mid] < p + 1) a = mid + 1; else b2 = mid; } hi = a; }
    for (int c = threadIdx.x; c < ncol; c += 256) {
        float mx = -INFINITY;
        for (int i = lo; i < hi; ++i)
            mx = fmaxf(mx, b2f(pooled[(size_t)nodes[i] * ldp + c]));
        if (BFOUT) ((u16*)outv)[(size_t)p * ldo + c] = f2b(mx);
        else       ((float*)outv)[(size_t)p * ldo + c] = mx;
    }
}

// ---------- gather conj rows into second half of output (bf16 -> fp32) ----
__global__ __launch_bounds__(768) void gather_conj(
    const u16* __restrict__ cs, const int* __restrict__ p2c,
    float* __restrict__ out)
{
    int p = blockIdx.x;
    int c = threadIdx.x;
    out[(size_t)p * (2 * CD) + CD + c] = b2f(cs[(size_t)p2c[p] * CD + c]);
}

extern "C" void kernel_launch(void* const* d_in, const int* in_sizes, int n_in,
                              void* d_out, int out_size, void* d_ws, size_t ws_size,
                              hipStream_t stream) {
    const float* node_states     = (const float*)d_in[0];
    const int*   node_types      = (const int*)d_in[1];
    const int*   pair_conj       = (const int*)d_in[2];
    const int*   pair_prem       = (const int*)d_in[3];
    const int*   pool_prem_nodes = (const int*)d_in[4];
    const int*   pool_prem_seg   = (const int*)d_in[5];
    const int*   pool_conj_nodes = (const int*)d_in[6];
    const int*   pool_conj_seg   = (const int*)d_in[7];
    const int*   prem2conj       = (const int*)d_in[8];
    const float* ln_g  = (const float*)d_in[9];
    const float* ln_b  = (const float*)d_in[10];
    const float* emb_p = (const float*)d_in[11];
    const float* wp_w  = (const float*)d_in[12];
    const float* wp_b  = (const float*)d_in[13];
    const float* emb_c = (const float*)d_in[14];
    const float* wc_w  = (const float*)d_in[15];
    const float* wc_b  = (const float*)d_in[16];
    const float* Wq_p  = (const float*)d_in[17];
    const float* Wk_p  = (const float*)d_in[18];
    const float* Wv_p  = (const float*)d_in[19];
    const float* Wo_p  = (const float*)d_in[20];
    const float* Wq_c  = (const float*)d_in[21];
    const float* Wk_c  = (const float*)d_in[22];
    const float* Wv_c  = (const float*)d_in[23];
    const float* Wo_c  = (const float*)d_in[24];
    const float* W_dag = (const float*)d_in[25];
    const float* b_dag = (const float*)d_in[26];
    float* out = (float*)d_out;

    // ===== workspace layout (bytes) =====
    char* ws = (char*)d_ws;
    size_t o = 0;
    u16* x_bf  = (u16*)(ws + o); o += (size_t)N_NODES * DIM * 2;   // 51.2 MB
    u16* comb  = (u16*)(ws + o); o += (size_t)N_NODES * ATT * 2;   // 102.4 MB
    u16* R     = (u16*)(ws + o); o += (size_t)N_NODES * ATT * 2;   // 102.4 MB (agg)
    char* csrb = ws + o;         o += 8000000;                     // CSR scratch
    u16* conj_sets = (u16*)(ws + o); o += (size_t)PC_SEG * CD * 2; // 1.57 MB (fallback)
    const size_t WS_NEEDED = o;  // 265,572,864

    if (ws_size < WS_NEEDED) {
        fill_val_k<<<(out_size + 255) / 256, 256, 0, stream>>>(out, out_size, (float)ws_size);
        return;
    }
    // graduated head-batch: qkv_batch buffer [N][batch*192] bf16 appended
    u16* qkv_all = (u16*)(ws + WS_NEEDED);
    int batch = 1;
    if (ws_size >= WS_NEEDED + (size_t)N_NODES * 1536 * 2)      batch = 8;
    else if (ws_size >= WS_NEEDED + (size_t)N_NODES * 768 * 2)  batch = 4;
    else if (ws_size >= WS_NEEDED + (size_t)N_NODES * 384 * 2)  batch = 2;
    // fused dual-Wo path (batch-2 qkv chunks): qkv [N][384] (76.8 MB) +
    // aggC [N][512] (102.4 MB) beyond base = 444.77 MB total.
    u16* aggC = qkv_all + (size_t)N_NODES * 384;   // u16 elements
    const bool fused = (ws_size >= WS_NEEDED + (size_t)N_NODES * 384 * 2
                                 + (size_t)N_NODES * ATT * 2);
    // single-pass dag: pooled [N][768] at R's offset (153.6 MB), spanning
    // R + csrb + conj_sets + first 41.6 MB of qkv region (all dead by then);
    // ends at 307.2 MB; conj_sets relocated to 307.2 MB.
    u16* pooled_big = (u16*)(ws + 153600000);
    u16* conj2      = (u16*)(ws + 307200000);
    const bool dag_single = (ws_size >= 307200000 + (size_t)PC_SEG * CD * 2);

    u16* agg    = R;
    u16* pooled = R;   // 2-pass fallback only (ld=384)
    int* c_counts[2], *c_offs[2], *c_cur[2], *c_tgt[2];
    for (int d = 0; d < 2; ++d) {
        char* base = csrb + (size_t)d * 2200000;
        c_counts[d] = (int*)(base + 0);
        c_offs[d]   = (int*)(base + 400000);
        c_cur[d]    = (int*)(base + 800000);
        c_tgt[d]    = (int*)(base + 1200000);
    }
    int* bsums = (int*)(csrb + 4400000);

    // ===== d_out scratch (all dead before first final-output write) =====
    char* ob = (char*)d_out;
    u16* qkv     = (u16*)(ob + 0);          // 38.4 MB [N][q|k|v] one head
    float* gtab_p = (float*)(ob + 38400000);
    float* gtab_c = (float*)(ob + 38531072);
    u16* wqkv_t  = (u16*)(ob + 38662144);   // 1.57 MB (2 dirs)
    u16* wo_t    = (u16*)(ob + 40235008);   // 2.10 MB (2 dirs)
    u16* wdag_t  = (u16*)(ob + 42332160);   // 1.18 MB (consumed before out writes)
    // end 43,511,808 <= 50,331,648

    // ---- prep ----
    layernorm_k<<<N_NODES, 64, 0, stream>>>(node_states, ln_g, ln_b, x_bf);
    gate_table_k<<<TYPE_CT, ATT, 0, stream>>>(emb_p, wp_w, wp_b, gtab_p);
    gate_table_k<<<TYPE_CT, ATT, 0, stream>>>(emb_c, wc_w, wc_b, gtab_c);
    wqkv_cvt_k<<<(NH * 3 * HD * DIM + 255) / 256, 256, 0, stream>>>(
        Wq_p, Wk_p, Wv_p, wqkv_t);
    wqkv_cvt_k<<<(NH * 3 * HD * DIM + 255) / 256, 256, 0, stream>>>(
        Wq_c, Wk_c, Wv_c, wqkv_t + (size_t)NH * 3 * HD * DIM);
    wcvt_k<<<(ATT * ATT + 255) / 256, 256, 0, stream>>>(Wo_p, wo_t, ATT, ATT);
    wcvt_k<<<(ATT * ATT + 255) / 256, 256, 0, stream>>>(
        Wo_c, wo_t + (size_t)ATT * ATT, ATT, ATT);

    // ---- CSR build for both dirs (src = query side) ----
    const int NSCAN = (N_NODES + 255) / 256;  // 391
    for (int d = 0; d < 2; ++d) {
        const int* src = d ? pair_conj : pair_prem;
        const int* tgt = d ? pair_prem : pair_conj;
        hipMemsetAsync(c_counts[d], 0, 400000, stream);
        count_k<<<(E_PAIRS + 255) / 256, 256, 0, stream>>>(src, c_counts[d]);
        scan1_k<<<NSCAN, 256, 0, stream>>>(c_counts[d], c_offs[d], bsums);
        scan2_k<<<1, 512, 0, stream>>>(bsums, NSCAN);
        addcur_k<<<NSCAN, 256, 0, stream>>>(c_offs[d], bsums, c_cur[d]);
        scatter_k<<<(E_PAIRS + 255) / 256, 256, 0, stream>>>(src, tgt, c_cur[d], c_tgt[d]);
    }

    if (fused) {
        // batch-2 qkv chunks; both dirs' attention first, then one fused
        // dual-Wo GEMM (no comb RMW, single write pass).
        for (int dir = 0; dir < 2; ++dir) {
            const u16* wq_d = wqkv_t + (size_t)dir * NH * 3 * HD * DIM;
            u16* agg_d = dir ? aggC : agg;
            for (int hb = 0; hb < NH; hb += 2) {
                gemm_qkv_all<<<2 * MB64P, 256, 0, stream>>>(
                    x_bf, wq_d + (size_t)hb * 3 * HD * DIM, qkv_all, 2);
                attn_k<1><<<dim3((N_NODES + 3) / 4, 2), 256, 0, stream>>>(
                    qkv_all, 384, c_offs[dir], c_counts[dir], c_tgt[dir],
                    agg_d, hb);
            }
        }
        gemm_wo_fused<<<4 * MB64P, 256, 0, stream>>>(
            agg, aggC, wo_t, wo_t + (size_t)ATT * ATT, comb,
            gtab_p, gtab_c, node_types);
    } else {
        for (int dir = 0; dir < 2; ++dir) {
            const float* gt = dir ? gtab_c : gtab_p;
            const u16* wq_d = wqkv_t + (size_t)dir * NH * 3 * HD * DIM;
            const u16* wo_d = wo_t + (size_t)dir * ATT * ATT;

            if (batch > 1) {
                for (int hb = 0; hb < NH; hb += batch) {
                    gemm_qkv_all<<<batch * MB64P, 256, 0, stream>>>(
                        x_bf, wq_d + (size_t)hb * 3 * HD * DIM, qkv_all, batch);
                    attn_k<1><<<dim3((N_NODES + 3) / 4, batch), 256, 0, stream>>>(
                        qkv_all, batch * 192, c_offs[dir], c_counts[dir],
                        c_tgt[dir], agg, hb);
                }
            } else {
                for (int h = 0; h < NH; ++h) {
                    gemm_qkv<<<dim3(1, MB64), 256, 0, stream>>>(
                        x_bf, wq_d + (size_t)h * 3 * HD * DIM, qkv);
                    attn_k<0><<<(N_NODES + 3) / 4, 256, 0, stream>>>(
                        qkv, 192, c_offs[dir], c_counts[dir], c_tgt[dir], agg, h);
                }
            }

            if (dir == 0)
                gemm_wo_first<<<4 * MB64P, 256, 0, stream>>>(
                    agg, wo_d, comb, gt, node_types);
            else
                gemm_wo_acc<<<4 * MB64P, 256, 0, stream>>>(
                    agg, wo_d, comb, gt, node_types);
        }
    }

    // ---- W_dag -> bf16 [col][k] into d_out scratch (consumed pre-output) --
    wcvt_k<<<(CD * CD + 255) / 256, 256, 0, stream>>>(W_dag, wdag_t, CD, CD);

    if (dag_single) {
        // single-pass dag: pooled [N][768] spans R+csrb+conj+qkv head (dead)
        gemm_dag_full<<<6 * MB64P, 256, 0, stream>>>(
            x_bf, comb, wdag_t, pooled_big, b_dag);
        seg_max_k<0><<<P_SEG, 256, 0, stream>>>(
            pooled_big, CD, CD, pool_prem_nodes, pool_prem_seg, MP_SZ, out, 2 * CD);
        seg_max_k<1><<<PC_SEG, 256, 0, stream>>>(
            pooled_big, CD, CD, pool_conj_nodes, pool_conj_seg, MC_SZ, conj2, CD);
        gather_conj<<<P_SEG, CD, 0, stream>>>(conj2, prem2conj, out);
    } else {
        for (int c0 = 0; c0 < CD; c0 += 384) {
            gemm_dag<<<3 * MB64P, 256, 0, stream>>>(
                x_bf, comb, wdag_t + (size_t)c0 * CD, pooled, b_dag + c0);
            seg_max_k<0><<<P_SEG, 256, 0, stream>>>(
                pooled, 384, 384, pool_prem_nodes, pool_prem_seg, MP_SZ, out + c0, 2 * CD);
            seg_max_k<1><<<PC_SEG, 256, 0, stream>>>(
                pooled, 384, 384, pool_conj_nodes, pool_conj_seg, MC_SZ, conj_sets + c0, CD);
        }
        gather_conj<<<P_SEG, CD, 0, stream>>>(conj_sets, prem2conj, out);
    }
}

// Round 27
// 1980.695 us; speedup vs baseline: 1.0212x; 1.0015x over previous
//
#include <hip/hip_runtime.h>
#include <math.h>

#define N_NODES 100000
#define DIM 256
#define ATT 512
#define NH 8
#define HD 64
#define E_PAIRS 250000
#define TYPE_CT 64
#define TS 64
#define P_SEG 8192
#define PC_SEG 1024
#define MP_SZ 131072
#define MC_SZ 16384
#define CD 768  // DIM + ATT

typedef unsigned short u16;
typedef __attribute__((ext_vector_type(8))) short short8v;
typedef __attribute__((ext_vector_type(4))) float floatx4;

// ---------- bf16 helpers (RNE) ----------
__device__ __forceinline__ u16 f2b(float f) {
    unsigned u = __float_as_uint(f);
    return (u16)((u + 0x7FFFu + ((u >> 16) & 1u)) >> 16);
}
__device__ __forceinline__ float b2f(u16 h) {
    return __uint_as_float(((unsigned)h) << 16);
}

template<int N>
__device__ __forceinline__ void waitcnt_vm() {
    asm volatile("s_waitcnt vmcnt(%0)" :: "n"(N) : "memory");
}
// s_barrier WITH compiler memory fence (raw builtin is exec-only).
__device__ __forceinline__ void barrier_fence() {
    asm volatile("s_barrier" ::: "memory");
    __builtin_amdgcn_sched_barrier(0);
}

// XCD-grouping remap: all gx column-blocks of one A-panel (same y) get
// flat%8 == y%8 -> same XCD L2 -> panel fetched once, not gx times.
__device__ __forceinline__ void remap8(int flat, int gx, int& bx, int& by) {
    int yc = flat & 7;
    int t = flat >> 3;
    bx = t % gx;
    by = yc + 8 * (t / gx);
}

// ---------- guard: report ws_size via output ----------
__global__ __launch_bounds__(256) void fill_val_k(float* out, int n, float v) {
    int i = blockIdx.x * 256 + threadIdx.x;
    if (i < n) out[i] = v;
}

// ---------- LayerNorm -> bf16: one wave per row ----------
__global__ __launch_bounds__(64) void layernorm_k(
    const float* __restrict__ ns, const float* __restrict__ g,
    const float* __restrict__ b, u16* __restrict__ x)
{
    int row = blockIdx.x;
    int lane = threadIdx.x;
    float4 v = ((const float4*)(ns + (size_t)row * DIM))[lane];
    float sum = v.x + v.y + v.z + v.w;
    #pragma unroll
    for (int off = 32; off >= 1; off >>= 1) sum += __shfl_xor(sum, off);
    float mu = sum * (1.0f / DIM);
    float dx = v.x - mu, dy = v.y - mu, dz = v.z - mu, dw = v.w - mu;
    float sq = dx * dx + dy * dy + dz * dz + dw * dw;
    #pragma unroll
    for (int off = 32; off >= 1; off >>= 1) sq += __shfl_xor(sq, off);
    float rs = rsqrtf(sq * (1.0f / DIM) + 1e-5f);
    float4 gg = ((const float4*)g)[lane];
    float4 bb = ((const float4*)b)[lane];
    u16 o4[4];
    o4[0] = f2b(dx * rs * gg.x + bb.x);
    o4[1] = f2b(dy * rs * gg.y + bb.y);
    o4[2] = f2b(dz * rs * gg.z + bb.z);
    o4[3] = f2b(dw * rs * gg.w + bb.w);
    *(uint2*)(x + (size_t)row * DIM + lane * 4) = *(uint2*)o4;
}

// ---------- per-type gate table: sigmoid(emb[t] @ W + b) ----------
__global__ __launch_bounds__(512) void gate_table_k(
    const float* __restrict__ emb, const float* __restrict__ w,
    const float* __restrict__ wb, float* __restrict__ tab)
{
    int t = blockIdx.x;
    int a = threadIdx.x;
    float acc = wb[a];
    #pragma unroll 8
    for (int s = 0; s < TS; ++s) acc += emb[t * TS + s] * w[s * ATT + a];
    tab[t * ATT + a] = 1.0f / (1.0f + expf(-acc));
}

// ---------- weight prep: fp32 [K][N] -> bf16 [N][K] ----------
__global__ __launch_bounds__(256) void wcvt_k(
    const float* __restrict__ W, u16* __restrict__ Bt, int K, int N)
{
    int idx = blockIdx.x * 256 + threadIdx.x;
    if (idx >= K * N) return;
    int c = idx / K, k = idx - c * K;
    Bt[idx] = f2b(W[(size_t)k * N + c]);
}

// ---------- QKV weight prep: [H][D][HD] x3 -> [h][{q,k,v}*64][D] bf16 ------
__global__ __launch_bounds__(256) void wqkv_cvt_k(
    const float* __restrict__ Wq, const float* __restrict__ Wk,
    const float* __restrict__ Wv, u16* __restrict__ outp)
{
    int idx = blockIdx.x * 256 + threadIdx.x;  // idx = ((h*3+m)*64+c)*256 + k
    if (idx >= NH * 3 * HD * DIM) return;
    int k = idx & (DIM - 1);
    int c = (idx >> 8) & (HD - 1);
    int hm = idx >> 14;          // = h*3 + m
    int m = hm % 3;
    int h = hm / 3;
    const float* W = (m == 0) ? Wq : ((m == 1) ? Wk : Wv);
    outp[idx] = f2b(W[((size_t)h * DIM + k) * HD + c]);
}

// ---------- MFMA bf16 GEMM, DEPTH-buffer counted-vmcnt pipeline ----------
// Round-13/16/23 proven config. BM x (32*WN) tile, BK=32, 4 waves, DEPTH-
// buffered linear LDS, global_load_lds 16B staging, chunk-XOR swizzle,
// direct-store epilogue (LDS-staged epilogue abandoned: rounds 24-26).
template<int BM, int WN, int DEPTH, int EPI>
__device__ __forceinline__ void gemm_body3(
    int bm, int bn,
    const u16* __restrict__ A, int lda,
    const u16* __restrict__ A2, int lda2, int K1,
    const u16* __restrict__ Bt, int ldb,
    u16* __restrict__ C, int ldc,
    int M, int K,
    const float* __restrict__ bias,
    const float* __restrict__ gateTab,
    const int* __restrict__ types)
{
    constexpr int BN = 32 * WN;
    constexpr int AR = BM / 64;
    constexpr int BR = BN / 64;
    constexpr int LA = AR + BR;
    constexpr int AF = BM / 32;
    __shared__ u16 As[DEPTH][BM * 32];
    __shared__ u16 Bs[DEPTH][BN * 32];
    const int tid = threadIdx.x;
    const int wave = tid >> 6, lane = tid & 63;
    const int wm = (wave >> 1) * (BM / 2), wn = (wave & 1) * 16 * WN;
    const int srow = tid >> 2;
    const int skk = (((tid & 3) ^ ((srow >> 1) & 3)) * 8);
    floatx4 acc[AF][WN] = {};

    auto stage = [&](int buf, int k0) {
        #pragma unroll
        for (int rnd = 0; rnd < AR; ++rnd) {
            int grow = bm + srow + rnd * 64;
            if (grow > M - 1) grow = M - 1;
            int gk = k0 + skk;
            const u16* src;
            if (EPI == 2 && gk >= K1) src = A2 + (size_t)grow * lda2 + (gk - K1);
            else                      src = A + (size_t)grow * lda + gk;
            __builtin_amdgcn_global_load_lds(
                (const __attribute__((address_space(1))) void*)src,
                (__attribute__((address_space(3))) void*)(&As[buf][rnd * 2048 + wave * 512]),
                16, 0, 0);
        }
        #pragma unroll
        for (int rnd = 0; rnd < BR; ++rnd) {
            const u16* src = Bt + (size_t)(bn + srow + rnd * 64) * ldb + k0 + skk;
            __builtin_amdgcn_global_load_lds(
                (const __attribute__((address_space(1))) void*)src,
                (__attribute__((address_space(3))) void*)(&Bs[buf][rnd * 2048 + wave * 512]),
                16, 0, 0);
        }
    };

    const int NS = K >> 5;
    #pragma unroll
    for (int p = 0; p < DEPTH - 1; ++p)
        if (p < NS) stage(p, p * 32);
    const int rr = lane & 15;
    const int cq = lane >> 4;
    int cur = 0;
    for (int is = 0; is < NS; ++is) {
        int pend = NS - 1 - is;
        if (pend > DEPTH - 2) pend = DEPTH - 2;
        if (pend >= 2)      waitcnt_vm<2 * LA>();
        else if (pend == 1) waitcnt_vm<LA>();
        else                waitcnt_vm<0>();
        barrier_fence();
        if (is + DEPTH - 1 < NS) stage((cur + DEPTH - 1) % DEPTH, (is + DEPTH - 1) * 32);
        short8v a[AF], b[WN];
        #pragma unroll
        for (int i = 0; i < AF; ++i) {
            int ar = wm + i * 16 + rr;
            a[i] = *(const short8v*)&As[cur][ar * 32 + ((cq ^ ((ar >> 1) & 3)) * 8)];
        }
        #pragma unroll
        for (int j = 0; j < WN; ++j) {
            int br = wn + j * 16 + rr;
            b[j] = *(const short8v*)&Bs[cur][br * 32 + ((cq ^ ((br >> 1) & 3)) * 8)];
        }
        #pragma unroll
        for (int i = 0; i < AF; ++i)
            #pragma unroll
            for (int j = 0; j < WN; ++j)
                acc[i][j] = __builtin_amdgcn_mfma_f32_16x16x32_bf16(
                    a[i], b[j], acc[i][j], 0, 0, 0);
        cur = (cur + 1) % DEPTH;
    }
    // epilogue: direct stores (C/D layout col=lane&15, row=(lane>>4)*4+reg)
    #pragma unroll
    for (int i = 0; i < AF; ++i) {
        #pragma unroll
        for (int j = 0; j < WN; ++j) {
            #pragma unroll
            for (int q = 0; q < 4; ++q) {
                int row = bm + wm + i * 16 + (lane >> 4) * 4 + q;
                if (row >= M) continue;
                int col = bn + wn + j * 16 + (lane & 15);
                float v = acc[i][j][q];
                size_t idx = (size_t)row * ldc + col;
                if (EPI == 0) C[idx] = f2b(v);
                else if (EPI == 1) {
                    float g = gateTab[types[row] * ATT + col];
                    C[idx] = f2b(b2f(C[idx]) + g * v);
                } else if (EPI == 3) {
                    float g = gateTab[types[row] * ATT + col];
                    C[idx] = f2b(g * v);
                } else {
                    C[idx] = f2b(tanhf(v + bias[col]));
                }
            }
        }
    }
}

#define MB64 1563          // (N_NODES + 63) / 64
#define MB64P 1568         // padded to multiple of 8 for remap8

// ---------- named GEMM wrappers (round-16 proven configs) ----------
__global__ __launch_bounds__(256) void gemm_qkv(
    const u16* __restrict__ A, const u16* __restrict__ Bt, u16* __restrict__ C)
{
    gemm_body3<64, 6, 3, 0>(blockIdx.y * 64, 0,
                            A, DIM, nullptr, 0, 1 << 30, Bt, DIM, C, 192,
                            N_NODES, DIM, nullptr, nullptr, nullptr);
}
// batched-heads QKV: gx 192-col blocks (one per head in batch), ldc = gx*192
__global__ __launch_bounds__(256) void gemm_qkv_all(
    const u16* __restrict__ A, const u16* __restrict__ Bt, u16* __restrict__ C,
    int gx)
{
    int bx, by; remap8(blockIdx.x, gx, bx, by);
    if (by >= MB64) return;
    gemm_body3<64, 6, 3, 0>(by * 64, bx * 192,
                            A, DIM, nullptr, 0, 1 << 30, Bt, DIM, C, gx * 192,
                            N_NODES, DIM, nullptr, nullptr, nullptr);
}
__global__ __launch_bounds__(256) void gemm_wo_first(
    const u16* __restrict__ A, const u16* __restrict__ Bt, u16* __restrict__ C,
    const float* __restrict__ gateTab, const int* __restrict__ types)
{
    int bx, by; remap8(blockIdx.x, 4, bx, by);
    if (by >= MB64) return;
    gemm_body3<64, 4, 3, 3>(by * 64, bx * 128,
                            A, ATT, nullptr, 0, 1 << 30, Bt, ATT, C, ATT,
                            N_NODES, ATT, nullptr, gateTab, types);
}
__global__ __launch_bounds__(256) void gemm_wo_acc(
    const u16* __restrict__ A, const u16* __restrict__ Bt, u16* __restrict__ C,
    const float* __restrict__ gateTab, const int* __restrict__ types)
{
    int bx, by; remap8(blockIdx.x, 4, bx, by);
    if (by >= MB64) return;
    gemm_body3<64, 4, 3, 1>(by * 64, bx * 128,
                            A, ATT, nullptr, 0, 1 << 30, Bt, ATT, C, ATT,
                            N_NODES, ATT, nullptr, gateTab, types);
}
// dag over a 384-col chunk (2-pass fallback): gx=3
__global__ __launch_bounds__(256) void gemm_dag(
    const u16* __restrict__ A, const u16* __restrict__ A2,
    const u16* __restrict__ Bt, u16* __restrict__ C,
    const float* __restrict__ bias)
{
    int bx, by; remap8(blockIdx.x, 3, bx, by);
    if (by >= MB64) return;
    gemm_body3<64, 4, 3, 2>(by * 64, bx * 128,
                            A, DIM, A2, ATT, DIM, Bt, CD, C, 384,
                            N_NODES, CD, bias, nullptr, nullptr);
}
// dag full 768-col single pass: gx=6, ldc=768
__global__ __launch_bounds__(256) void gemm_dag_full(
    const u16* __restrict__ A, const u16* __restrict__ A2,
    const u16* __restrict__ Bt, u16* __restrict__ C,
    const float* __restrict__ bias)
{
    int bx, by; remap8(blockIdx.x, 6, bx, by);
    if (by >= MB64) return;
    gemm_body3<64, 4, 3, 2>(by * 64, bx * 128,
                            A, DIM, A2, ATT, DIM, Bt, CD, C, CD,
                            N_NODES, CD, bias, nullptr, nullptr);
}

// ---------- CSR build ----------
__global__ __launch_bounds__(256) void count_k(
    const int* __restrict__ src, int* __restrict__ counts)
{
    int e = blockIdx.x * 256 + threadIdx.x;
    if (e < E_PAIRS) atomicAdd(&counts[src[e]], 1);
}
__global__ __launch_bounds__(256) void scan1_k(
    const int* __restrict__ counts, int* __restrict__ offs, int* __restrict__ bsums)
{
    __shared__ int sm[256];
    int i = blockIdx.x * 256 + threadIdx.x;
    int v = (i < N_NODES) ? counts[i] : 0;
    sm[threadIdx.x] = v;
    __syncthreads();
    for (int d = 1; d < 256; d <<= 1) {
        int t = (threadIdx.x >= d) ? sm[threadIdx.x - d] : 0;
        __syncthreads();
        sm[threadIdx.x] += t;
        __syncthreads();
    }
    if (i < N_NODES) offs[i] = sm[threadIdx.x] - v;   // exclusive
    if (threadIdx.x == 255) bsums[blockIdx.x] = sm[255];
}
__global__ __launch_bounds__(512) void scan2_k(int* __restrict__ bsums, int nb)
{
    __shared__ int sm[512];
    int tx = threadIdx.x;
    int v = (tx < nb) ? bsums[tx] : 0;
    sm[tx] = v;
    __syncthreads();
    for (int d = 1; d < 512; d <<= 1) {
        int t = (tx >= d) ? sm[tx - d] : 0;
        __syncthreads();
        sm[tx] += t;
        __syncthreads();
    }
    if (tx < nb) bsums[tx] = sm[tx] - v;              // exclusive
}
__global__ __launch_bounds__(256) void addcur_k(
    int* __restrict__ offs, const int* __restrict__ bsums, int* __restrict__ cur)
{
    int i = blockIdx.x * 256 + threadIdx.x;
    if (i >= N_NODES) return;
    int o = offs[i] + bsums[i >> 8];
    offs[i] = o;
    cur[i] = o;
}
__global__ __launch_bounds__(256) void scatter_k(
    const int* __restrict__ src, const int* __restrict__ tgt,
    int* __restrict__ cur, int* __restrict__ csr_tgt)
{
    int e = blockIdx.x * 256 + threadIdx.x;
    if (e >= E_PAIRS) return;
    int p = atomicAdd(&cur[src[e]], 1);
    csr_tgt[p] = tgt[e];
}

// ---------- fused segment attention: wave per node, online softmax ---------
// 2-deep edge pipeline (round-16/18 proven). MULTI=1: qkv [N][ld] multi-head,
// head = h_in + blockIdx.y, base = qkv + blockIdx.y*192. MULTI=0: [N][192].
template<int MULTI>
__global__ __launch_bounds__(256) void attn_k(
    const u16* __restrict__ qkv, int ld,
    const int* __restrict__ offs, const int* __restrict__ counts,
    const int* __restrict__ csr_tgt, u16* __restrict__ agg, int h_in)
{
    int s = blockIdx.x * 4 + (threadIdx.x >> 6);
    if (s >= N_NODES) return;
    int hy = MULTI ? blockIdx.y : 0;
    int h = h_in + hy;
    const u16* base = qkv + hy * 192;
    int lane = threadIdx.x & 63;
    float q = b2f(base[(size_t)s * ld + lane]) * 0.125f;  // fold 1/sqrt(64)
    int lo = offs[s], deg = counts[s];
    float m = -INFINITY, l = 0.0f, acc = 0.0f;
    if (deg > 0) {
        int t0 = csr_tgt[lo];
        u16 kc = base[(size_t)t0 * ld + 64 + lane];
        u16 vc = base[(size_t)t0 * ld + 128 + lane];
        for (int i = 0; i < deg; ++i) {
            u16 kn = 0, vn = 0;
            if (i + 1 < deg) {
                int tn = csr_tgt[lo + i + 1];
                kn = base[(size_t)tn * ld + 64 + lane];
                vn = base[(size_t)tn * ld + 128 + lane];
            }
            float p = q * b2f(kc);
            #pragma unroll
            for (int off = 32; off >= 1; off >>= 1) p += __shfl_xor(p, off);
            float mn = fmaxf(m, p);
            float sc = expf(m - mn);    // m=-inf first iter -> 0
            float w  = expf(p - mn);
            l = l * sc + w;
            acc = acc * sc + w * b2f(vc);
            m = mn;
            kc = kn; vc = vn;
        }
    }
    float r = (deg > 0) ? acc / l : 0.0f;
    agg[(size_t)s * ATT + h * HD + lane] = f2b(r);
}

// ---------- segment max over ncol cols of pooled (bf16, ld stride) --------
template<int BFOUT>
__global__ __launch_bounds__(256) void seg_max_k(
    const u16* __restrict__ pooled, int ldp, int ncol,
    const int* __restrict__ nodes, const int* __restrict__ seg, int total,
    void* __restrict__ outv, int ldo)
{
    int p = blockIdx.x;
    int lo, hi;
    { int a = 0, b2 = total; while (a < b2) { int mid = (a + b2) >> 1; if (seg[mid] < p) a = mid + 1; else b2 = mid; } lo = a; }
    { int a = lo, b2 = total; while (a < b2) { int mid = (a + b2) >> 1; if (seg[mid] < p + 1) a = mid + 1; else b2 = mid; } hi = a; }
    for (int c = threadIdx.x; c < ncol; c += 256) {
        float mx = -INFINITY;
        for (int i = lo; i < hi; ++i)
            mx = fmaxf(mx, b2f(pooled[(size_t)nodes[i] * ldp + c]));
        if (BFOUT) ((u16*)outv)[(size_t)p * ldo + c] = f2b(mx);
        else       ((float*)outv)[(size_t)p * ldo + c] = mx;
    }
}

// ---------- gather conj rows into second half of output (bf16 -> fp32) ----
__global__ __launch_bounds__(768) void gather_conj(
    const u16* __restrict__ cs, const int* __restrict__ p2c,
    float* __restrict__ out)
{
    int p = blockIdx.x;
    int c = threadIdx.x;
    out[(size_t)p * (2 * CD) + CD + c] = b2f(cs[(size_t)p2c[p] * CD + c]);
}

extern "C" void kernel_launch(void* const* d_in, const int* in_sizes, int n_in,
                              void* d_out, int out_size, void* d_ws, size_t ws_size,
                              hipStream_t stream) {
    const float* node_states     = (const float*)d_in[0];
    const int*   node_types      = (const int*)d_in[1];
    const int*   pair_conj       = (const int*)d_in[2];
    const int*   pair_prem       = (const int*)d_in[3];
    const int*   pool_prem_nodes = (const int*)d_in[4];
    const int*   pool_prem_seg   = (const int*)d_in[5];
    const int*   pool_conj_nodes = (const int*)d_in[6];
    const int*   pool_conj_seg   = (const int*)d_in[7];
    const int*   prem2conj       = (const int*)d_in[8];
    const float* ln_g  = (const float*)d_in[9];
    const float* ln_b  = (const float*)d_in[10];
    const float* emb_p = (const float*)d_in[11];
    const float* wp_w  = (const float*)d_in[12];
    const float* wp_b  = (const float*)d_in[13];
    const float* emb_c = (const float*)d_in[14];
    const float* wc_w  = (const float*)d_in[15];
    const float* wc_b  = (const float*)d_in[16];
    const float* Wq_p  = (const float*)d_in[17];
    const float* Wk_p  = (const float*)d_in[18];
    const float* Wv_p  = (const float*)d_in[19];
    const float* Wo_p  = (const float*)d_in[20];
    const float* Wq_c  = (const float*)d_in[21];
    const float* Wk_c  = (const float*)d_in[22];
    const float* Wv_c  = (const float*)d_in[23];
    const float* Wo_c  = (const float*)d_in[24];
    const float* W_dag = (const float*)d_in[25];
    const float* b_dag = (const float*)d_in[26];
    float* out = (float*)d_out;

    // ===== workspace layout (bytes) =====
    char* ws = (char*)d_ws;
    size_t o = 0;
    u16* x_bf  = (u16*)(ws + o); o += (size_t)N_NODES * DIM * 2;   // 51.2 MB
    u16* comb  = (u16*)(ws + o); o += (size_t)N_NODES * ATT * 2;   // 102.4 MB
    u16* R     = (u16*)(ws + o); o += (size_t)N_NODES * ATT * 2;   // 102.4 MB (agg)
    char* csrb = ws + o;         o += 8000000;                     // CSR scratch
    u16* conj_sets = (u16*)(ws + o); o += (size_t)PC_SEG * CD * 2; // 1.57 MB (fallback)
    const size_t WS_NEEDED = o;  // 265,572,864

    if (ws_size < WS_NEEDED) {
        fill_val_k<<<(out_size + 255) / 256, 256, 0, stream>>>(out, out_size, (float)ws_size);
        return;
    }
    // graduated head-batch: qkv_batch buffer [N][batch*192] bf16 appended
    u16* qkv_all = (u16*)(ws + WS_NEEDED);
    int batch = 1;
    if (ws_size >= WS_NEEDED + (size_t)N_NODES * 1536 * 2)      batch = 8;
    else if (ws_size >= WS_NEEDED + (size_t)N_NODES * 768 * 2)  batch = 4;
    else if (ws_size >= WS_NEEDED + (size_t)N_NODES * 384 * 2)  batch = 2;
    // single-pass dag: pooled [N][768] at R's offset (153.6 MB), spanning
    // R + csrb + conj_sets + first 41.6 MB of qkv region (all dead by then);
    // ends at 307.2 MB; conj_sets relocated to 307.2 MB. wdag_t lives in
    // d_out scratch (NOT inside the pooled span — round-23 latent race fix).
    u16* pooled_big = (u16*)(ws + 153600000);
    u16* conj2      = (u16*)(ws + 307200000);
    const bool dag_single = (ws_size >= 307200000 + (size_t)PC_SEG * CD * 2);

    u16* agg    = R;
    u16* pooled = R;   // 2-pass fallback only (ld=384)
    int* c_counts[2], *c_offs[2], *c_cur[2], *c_tgt[2];
    for (int d = 0; d < 2; ++d) {
        char* base = csrb + (size_t)d * 2200000;
        c_counts[d] = (int*)(base + 0);
        c_offs[d]   = (int*)(base + 400000);
        c_cur[d]    = (int*)(base + 800000);
        c_tgt[d]    = (int*)(base + 1200000);
    }
    int* bsums = (int*)(csrb + 4400000);

    // ===== d_out scratch (all dead before first final-output write) =====
    char* ob = (char*)d_out;
    u16* qkv     = (u16*)(ob + 0);          // 38.4 MB [N][q|k|v] one head
    float* gtab_p = (float*)(ob + 38400000);
    float* gtab_c = (float*)(ob + 38531072);
    u16* wqkv_t  = (u16*)(ob + 38662144);   // 1.57 MB (2 dirs)
    u16* wo_t    = (u16*)(ob + 40235008);   // 2.10 MB (2 dirs)
    u16* wdag_t  = (u16*)(ob + 42332160);   // 1.18 MB (consumed before out writes)
    // end 43,511,808 <= 50,331,648

    // ---- prep ----
    layernorm_k<<<N_NODES, 64, 0, stream>>>(node_states, ln_g, ln_b, x_bf);
    gate_table_k<<<TYPE_CT, ATT, 0, stream>>>(emb_p, wp_w, wp_b, gtab_p);
    gate_table_k<<<TYPE_CT, ATT, 0, stream>>>(emb_c, wc_w, wc_b, gtab_c);
    wqkv_cvt_k<<<(NH * 3 * HD * DIM + 255) / 256, 256, 0, stream>>>(
        Wq_p, Wk_p, Wv_p, wqkv_t);
    wqkv_cvt_k<<<(NH * 3 * HD * DIM + 255) / 256, 256, 0, stream>>>(
        Wq_c, Wk_c, Wv_c, wqkv_t + (size_t)NH * 3 * HD * DIM);
    wcvt_k<<<(ATT * ATT + 255) / 256, 256, 0, stream>>>(Wo_p, wo_t, ATT, ATT);
    wcvt_k<<<(ATT * ATT + 255) / 256, 256, 0, stream>>>(
        Wo_c, wo_t + (size_t)ATT * ATT, ATT, ATT);

    // ---- CSR build for both dirs (src = query side) ----
    const int NSCAN = (N_NODES + 255) / 256;  // 391
    for (int d = 0; d < 2; ++d) {
        const int* src = d ? pair_conj : pair_prem;
        const int* tgt = d ? pair_prem : pair_conj;
        hipMemsetAsync(c_counts[d], 0, 400000, stream);
        count_k<<<(E_PAIRS + 255) / 256, 256, 0, stream>>>(src, c_counts[d]);
        scan1_k<<<NSCAN, 256, 0, stream>>>(c_counts[d], c_offs[d], bsums);
        scan2_k<<<1, 512, 0, stream>>>(bsums, NSCAN);
        addcur_k<<<NSCAN, 256, 0, stream>>>(c_offs[d], bsums, c_cur[d]);
        scatter_k<<<(E_PAIRS + 255) / 256, 256, 0, stream>>>(src, tgt, c_cur[d], c_tgt[d]);
    }

    for (int dir = 0; dir < 2; ++dir) {
        const float* gt = dir ? gtab_c : gtab_p;
        const u16* wq_d = wqkv_t + (size_t)dir * NH * 3 * HD * DIM;
        const u16* wo_d = wo_t + (size_t)dir * ATT * ATT;

        if (batch > 1) {
            for (int hb = 0; hb < NH; hb += batch) {
                gemm_qkv_all<<<batch * MB64P, 256, 0, stream>>>(
                    x_bf, wq_d + (size_t)hb * 3 * HD * DIM, qkv_all, batch);
                attn_k<1><<<dim3((N_NODES + 3) / 4, batch), 256, 0, stream>>>(
                    qkv_all, batch * 192, c_offs[dir], c_counts[dir],
                    c_tgt[dir], agg, hb);
            }
        } else {
            for (int h = 0; h < NH; ++h) {
                gemm_qkv<<<dim3(1, MB64), 256, 0, stream>>>(
                    x_bf, wq_d + (size_t)h * 3 * HD * DIM, qkv);
                attn_k<0><<<(N_NODES + 3) / 4, 256, 0, stream>>>(
                    qkv, 192, c_offs[dir], c_counts[dir], c_tgt[dir], agg, h);
            }
        }

        if (dir == 0)
            gemm_wo_first<<<4 * MB64P, 256, 0, stream>>>(
                agg, wo_d, comb, gt, node_types);
        else
            gemm_wo_acc<<<4 * MB64P, 256, 0, stream>>>(
                agg, wo_d, comb, gt, node_types);
    }

    // ---- W_dag -> bf16 [col][k] into d_out scratch (consumed pre-output) --
    wcvt_k<<<(CD * CD + 255) / 256, 256, 0, stream>>>(W_dag, wdag_t, CD, CD);

    if (dag_single) {
        // single-pass dag: pooled [N][768] spans R+csrb+conj+qkv head (dead)
        gemm_dag_full<<<6 * MB64P, 256, 0, stream>>>(
            x_bf, comb, wdag_t, pooled_big, b_dag);
        seg_max_k<0><<<P_SEG, 256, 0, stream>>>(
            pooled_big, CD, CD, pool_prem_nodes, pool_prem_seg, MP_SZ, out, 2 * CD);
        seg_max_k<1><<<PC_SEG, 256, 0, stream>>>(
            pooled_big, CD, CD, pool_conj_nodes, pool_conj_seg, MC_SZ, conj2, CD);
        gather_conj<<<P_SEG, CD, 0, stream>>>(conj2, prem2conj, out);
    } else {
        for (int c0 = 0; c0 < CD; c0 += 384) {
            gemm_dag<<<3 * MB64P, 256, 0, stream>>>(
                x_bf, comb, wdag_t + (size_t)c0 * CD, pooled, b_dag + c0);
            seg_max_k<0><<<P_SEG, 256, 0, stream>>>(
                pooled, 384, 384, pool_prem_nodes, pool_prem_seg, MP_SZ, out + c0, 2 * CD);
            seg_max_k<1><<<PC_SEG, 256, 0, stream>>>(
                pooled, 384, 384, pool_conj_nodes, pool_conj_seg, MC_SZ, conj_sets + c0, CD);
        }
        gather_conj<<<P_SEG, CD, 0, stream>>>(conj_sets, prem2conj, out);
    }
}